// Round 5
// baseline (827.749 us; speedup 1.0000x reference)
//
#include <hip/hip_runtime.h>
#include <math.h>
#include <stdint.h>

#define NB 8
#define NS 256
#define NH 768
#define NL 20
#define NT 8
#define NE 300
#define NEGV (-10000.0f)
#define BS_ (NB*NS)          // 2048
#define NLT (NL*NT)          // 160
#define KTOT 1536            // [A1 | A2] concat K for the fused MFMA GEMM
#define NEP 320              // NE padded to mult of 32
#define NLTP 256             // NLT padded to mult of 128

typedef unsigned short u16;
typedef unsigned int   u32;
using short8v = __attribute__((ext_vector_type(8))) short;   // 8 bf16 = 4 VGPR
using f32x4   = __attribute__((ext_vector_type(4))) float;   // MFMA acc

__device__ __forceinline__ float fast_tanh(float x) {
  float e = __expf(2.0f * x);
  return 1.0f - 2.0f / (e + 1.0f);
}
// f32 -> bf16 round-to-nearest-even (bits)
__device__ __forceinline__ u16 f2bh(float f) {
  u32 u = __float_as_uint(f);
  return (u16)((u + 0x7fffu + ((u >> 16) & 1u)) >> 16);
}
__device__ __forceinline__ float bh2f(u16 h) {
  return __uint_as_float(((u32)h) << 16);
}
// async global->LDS, 16B per lane; lds ptr must be wave-uniform base
__device__ __forceinline__ void g2lds16(const void* g, void* s) {
  __builtin_amdgcn_global_load_lds((const __attribute__((address_space(1))) void*)g,
                                   (__attribute__((address_space(3))) void*)s, 16, 0, 0);
}
// Swizzle convention (ALL plane writers/readers): planes are row-major rows of
// K bf16.  Within each 64B k-block (32 values), the 16B chunk holding logical
// chunk c (c=0..3) is stored at position c ^ ((row>>1)&3).
__device__ __forceinline__ int swz_cb(int k0, int row) {
  return ((k0 >> 3) & 3) ^ ((row >> 1) & 3);
}

// ---------------------------------------------------------------------------
// f32 GEMM fallback (tier <2): C[m,n] = sum_k A[m,k]*B[n,k]
// ---------------------------------------------------------------------------
__global__ __launch_bounds__(256)
void gemm64(const float* __restrict__ A, int lda,
            const float* __restrict__ B, int ldb, int K,
            float* __restrict__ C, int ldc)
{
  __shared__ float As[16][64];
  __shared__ float Bs[16][64];
  const int t  = threadIdx.x;
  const int bm = blockIdx.x * 64, bn = blockIdx.y * 64;
  const int tm = t & 15, tn = t >> 4;
  const int lr = t >> 2;
  const int lk = (t & 3) * 4;
  float acc[4][4];
#pragma unroll
  for (int r = 0; r < 4; r++)
#pragma unroll
    for (int c = 0; c < 4; c++) acc[r][c] = 0.f;

  for (int kt = 0; kt < K; kt += 16) {
    float4 a4 = *(const float4*)(A + (size_t)(bm + lr) * lda + kt + lk);
    float4 b4 = *(const float4*)(B + (size_t)(bn + lr) * ldb + kt + lk);
    As[lk+0][lr] = a4.x; As[lk+1][lr] = a4.y; As[lk+2][lr] = a4.z; As[lk+3][lr] = a4.w;
    Bs[lk+0][lr] = b4.x; Bs[lk+1][lr] = b4.y; Bs[lk+2][lr] = b4.z; Bs[lk+3][lr] = b4.w;
    __syncthreads();
#pragma unroll
    for (int k = 0; k < 16; k++) {
      float av[4], bv[4];
#pragma unroll
      for (int r = 0; r < 4; r++) av[r] = As[k][tm*4 + r];
#pragma unroll
      for (int c = 0; c < 4; c++) bv[c] = Bs[k][tn*4 + c];
#pragma unroll
      for (int r = 0; r < 4; r++)
#pragma unroll
        for (int c = 0; c < 4; c++) acc[r][c] += av[r] * bv[c];
    }
    __syncthreads();
  }
#pragma unroll
  for (int r = 0; r < 4; r++)
#pragma unroll
    for (int c = 0; c < 4; c++)
      C[(size_t)(bm + tm*4 + r) * ldc + bn + tn*4 + c] = acc[r][c];
}

// ---- fallback small kernels (tier <3) ----
__global__ __launch_bounds__(256)
void lab_kernel(const float* __restrict__ label, const float* __restrict__ W2,
                float* __restrict__ lab)
{
  int lt = blockIdx.x;
  __shared__ __align__(16) float le[NE];
  for (int e = threadIdx.x; e < NE; e += 256) le[e] = label[(size_t)lt*NE + e];
  __syncthreads();
  for (int o = threadIdx.x; o < NH; o += 256) {
    const float4* wr = (const float4*)(W2 + (size_t)o*NE);
    const float4* l4 = (const float4*)le;
    float s = 0.f;
    for (int e = 0; e < NE/4; e++) {
      float4 a = l4[e], b = wr[e];
      s += a.x*b.x + a.y*b.y + a.z*b.z + a.w*b.w;
    }
    lab[(size_t)lt*NH + o] = s;
  }
}

__global__ __launch_bounds__(256)
void LB_kernel(const float* __restrict__ lab, const float* __restrict__ W5,
               float* __restrict__ LB)
{
  int lt = blockIdx.x;
  __shared__ __align__(16) float lr[NH];
  for (int h = threadIdx.x; h < NH; h += 256) lr[h] = lab[(size_t)lt*NH + h];
  __syncthreads();
  for (int o = threadIdx.x; o < NH; o += 256) {
    const float4* wr = (const float4*)(W5 + (size_t)o*3072 + NH);
    const float4* l4 = (const float4*)lr;
    float s = 0.f;
    for (int h = 0; h < NH/4; h++) {
      float4 a = l4[h], b = wr[h];
      s += a.x*b.x + a.y*b.y + a.z*b.z + a.w*b.w;
    }
    LB[(size_t)lt*NH + o] = s;
  }
}

__global__ __launch_bounds__(256)
void scores_kernel(const float* __restrict__ tkn, const float* __restrict__ lab,
                   const float* __restrict__ lmask, const float* __restrict__ imask,
                   float* __restrict__ aw, float* __restrict__ b_in)
{
  int bs = blockIdx.x;
  __shared__ __align__(16) float trow[NH];
  __shared__ float sc[NLT];
  __shared__ float mL[NL], iL[NL];
  for (int h = threadIdx.x; h < NH; h += 256) trow[h] = tkn[(size_t)bs*NH + h];
  __syncthreads();
  int j = threadIdx.x;
  if (j < NLT) {
    const float4* lrow = (const float4*)(lab + (size_t)j*NH);
    const float4* t4   = (const float4*)trow;
    float s = 0.f;
    for (int h = 0; h < NH/4; h++) {
      float4 a = t4[h], b = lrow[h];
      s += a.x*b.x + a.y*b.y + a.z*b.z + a.w*b.w;
    }
    s += (1.0f - lmask[j]) * NEGV;
    sc[j] = s;
  }
  __syncthreads();
  if (j < NL) {
    float m = sc[j*8];
    for (int t = 1; t < 8; t++) m = fmaxf(m, sc[j*8 + t]);
    float ssum = 0.f;
    for (int t = 0; t < 8; t++) ssum += __expf(sc[j*8 + t] - m);
    mL[j] = m; iL[j] = 1.0f / ssum;
    b_in[(size_t)bs*NL + j] = m + (1.0f - imask[bs]) * NEGV;
  }
  __syncthreads();
  if (j < NLT) aw[(size_t)bs*NLT + j] = __expf(sc[j] - mL[j >> 3]) * iL[j >> 3];
}

// tier3: softmax/aw from precomputed sc[BS_, NLT]
__global__ __launch_bounds__(256)
void aw_kernel(const float* __restrict__ sc_in, const float* __restrict__ lmask,
               const float* __restrict__ imask, float* __restrict__ aw,
               float* __restrict__ b_in)
{
  int bs = blockIdx.x;
  __shared__ float sc[NLT];
  __shared__ float mL[NL], iL[NL];
  int j = threadIdx.x;
  if (j < NLT) sc[j] = sc_in[(size_t)bs*NLT + j] + (1.0f - lmask[j]) * NEGV;
  __syncthreads();
  if (j < NL) {
    float m = sc[j*8];
    for (int t = 1; t < 8; t++) m = fmaxf(m, sc[j*8 + t]);
    float ssum = 0.f;
    for (int t = 0; t < 8; t++) ssum += __expf(sc[j*8 + t] - m);
    mL[j] = m; iL[j] = 1.0f / ssum;
    b_in[(size_t)bs*NL + j] = m + (1.0f - imask[bs]) * NEGV;
  }
  __syncthreads();
  if (j < NLT) aw[(size_t)bs*NLT + j] = __expf(sc[j] - mL[j >> 3]) * iL[j >> 3];
}

__global__ __launch_bounds__(256)
void softs_kernel(const float* __restrict__ b_in, float* __restrict__ bc)
{
  int b = blockIdx.x / NL, l = blockIdx.x % NL;
  int s = threadIdx.x;
  __shared__ float red[256];
  float v = b_in[((size_t)b*NS + s)*NL + l];
  red[s] = v; __syncthreads();
  for (int off = 128; off > 0; off >>= 1) {
    if (s < off) red[s] = fmaxf(red[s], red[s + off]);
    __syncthreads();
  }
  float m = red[0]; __syncthreads();
  float e = __expf(v - m);
  red[s] = e; __syncthreads();
  for (int off = 128; off > 0; off >>= 1) {
    if (s < off) red[s] += red[s + off];
    __syncthreads();
  }
  bc[((size_t)b*NS + s)*NL + l] = e / red[0];
}

// q2c[b,l,h] = sum_s bc[b,s,l]*tkn[b,s,h].  Grid (NB, NH/128): each block
// reads its tkn h-slice ONCE (vs 20x in the old per-(b,l) version).
__global__ __launch_bounds__(256)
void q2c_kernel2(const float* __restrict__ bc, const float* __restrict__ tkn,
                 float* __restrict__ q2c)
{
  const int b  = blockIdx.x;
  const int h0 = blockIdx.y * 128;
  const int t  = threadIdx.x;
  const int th = t & 127, half = t >> 7;
  __shared__ __align__(16) float bcS[NS*NL];        // 20 KB
  __shared__ __align__(16) float4 part[2*5*128];    // 20 KB
  for (int i = t; i < NS*NL; i += 256) bcS[i] = bc[(size_t)b*NS*NL + i];
  __syncthreads();
  float4 acc[5];
#pragma unroll
  for (int g = 0; g < 5; g++) acc[g] = {0.f, 0.f, 0.f, 0.f};
  const int h = h0 + th;
  for (int s = half*128; s < half*128 + 128; s++) {
    float tv = tkn[((size_t)b*NS + s)*NH + h];
    const float4* bl4 = (const float4*)(bcS + s*NL);
#pragma unroll
    for (int g = 0; g < 5; g++) {
      float4 w = bl4[g];
      acc[g].x += w.x*tv; acc[g].y += w.y*tv; acc[g].z += w.z*tv; acc[g].w += w.w*tv;
    }
  }
#pragma unroll
  for (int g = 0; g < 5; g++) part[(half*5 + g)*128 + th] = acc[g];
  __syncthreads();
  if (half == 0) {
#pragma unroll
    for (int g = 0; g < 5; g++) {
      float4 a = part[g*128 + th], c = part[(5 + g)*128 + th];
#pragma unroll
      for (int cc = 0; cc < 4; cc++) {
        int l = g*4 + cc;
        float v = ((const float*)&a)[cc] + ((const float*)&c)[cc];
        q2c[((size_t)(b*NL + l))*NH + h] = v;
      }
    }
  }
}

// ---------------------------------------------------------------------------
// OLD fused_out — fallback when ws can't even hold the fused-GEMM planes.
// ---------------------------------------------------------------------------
__global__ __launch_bounds__(256)
void fused_out(const float* __restrict__ tkn, const float* __restrict__ lab,
               const float* __restrict__ aw, const float* __restrict__ q2c,
               const float* __restrict__ T1, const float* __restrict__ LB,
               const float* __restrict__ W5, const float* __restrict__ b5,
               float* __restrict__ outp)
{
  const int t  = threadIdx.x;
  const int sq = blockIdx.x & 3;
  const int l  = (blockIdx.x >> 2) % NL;
  const int b  = blockIdx.x / (4 * NL);
  const int o0 = blockIdx.y * 64;
  const int s0 = sq * 64;
  const int tm = t & 15, tn = t >> 4;
  const int lr = t >> 2;
  const int lk = (t & 3) * 4;

  __shared__ float A1s[16][64];
  __shared__ float A2s[16][64];
  __shared__ float Cs[16][64];
  __shared__ float Ds[16][64];
  __shared__ float labS[NT][16];
  __shared__ float q2cS[16];
  __shared__ float awS[64][NT];
  __shared__ float LBS[NT][64];
  __shared__ float b5S[64];

  for (int i = t; i < 64*NT; i += 256) {
    int m = i >> 3, tt = i & 7;
    awS[m][tt] = aw[(size_t)(b*NS + s0 + m) * NLT + l*NT + tt];
  }
  for (int i = t; i < NT*64; i += 256) {
    int tt = i >> 6, n = i & 63;
    LBS[tt][n] = LB[(size_t)(l*NT + tt) * NH + o0 + n];
  }
  if (t < 64) b5S[t] = b5[o0 + t];

  float acc[4][4];
#pragma unroll
  for (int r = 0; r < 4; r++)
#pragma unroll
    for (int c = 0; c < 4; c++) acc[r][c] = 0.f;

  for (int kt = 0; kt < NH; kt += 16) {
    if (t < 128) { int tt = t >> 4, k = t & 15; labS[tt][k] = lab[(size_t)(l*NT + tt)*NH + kt + k]; }
    if (t < 16)  q2cS[t] = q2c[(size_t)(b*NL + l)*NH + kt + t];
    {
      float4 c4 = *(const float4*)(W5 + (size_t)(o0 + lr)*3072 + 1536 + kt + lk);
      Cs[lk+0][lr] = c4.x; Cs[lk+1][lr] = c4.y; Cs[lk+2][lr] = c4.z; Cs[lk+3][lr] = c4.w;
      float4 d4 = *(const float4*)(W5 + (size_t)(o0 + lr)*3072 + 2304 + kt + lk);
      Ds[lk+0][lr] = d4.x; Ds[lk+1][lr] = d4.y; Ds[lk+2][lr] = d4.z; Ds[lk+3][lr] = d4.w;
    }
    __syncthreads();
    {
      float4 t4 = *(const float4*)(tkn + (size_t)(b*NS + s0 + lr)*NH + kt + lk);
      float tv[4] = {t4.x, t4.y, t4.z, t4.w};
#pragma unroll
      for (int j = 0; j < 4; j++) {
        int k = lk + j;
        float c2 = 0.f;
#pragma unroll
        for (int tt = 0; tt < NT; tt++) c2 += awS[lr][tt] * labS[tt][k];
        A1s[k][lr] = tv[j] * c2;
        A2s[k][lr] = tv[j] * q2cS[k];
      }
    }
    __syncthreads();
#pragma unroll
    for (int k = 0; k < 16; k++) {
      float a1[4], a2[4], wc[4], wd[4];
#pragma unroll
      for (int r = 0; r < 4; r++) { a1[r] = A1s[k][tm*4 + r]; a2[r] = A2s[k][tm*4 + r]; }
#pragma unroll
      for (int c = 0; c < 4; c++) { wc[c] = Cs[k][tn*4 + c]; wd[c] = Ds[k][tn*4 + c]; }
#pragma unroll
      for (int r = 0; r < 4; r++)
#pragma unroll
        for (int c = 0; c < 4; c++)
          acc[r][c] += a1[r]*wc[c] + a2[r]*wd[c];
    }
    __syncthreads();
  }

#pragma unroll
  for (int r = 0; r < 4; r++) {
    int m = tm*4 + r;
    int s = s0 + m;
    size_t orow = ((size_t)(b*NS + s)*NL + l)*NH + o0;
    const float* T1r = T1 + (size_t)(b*NS + s)*NH + o0;
#pragma unroll
    for (int c = 0; c < 4; c++) {
      int n = tn*4 + c;
      float v = acc[r][c] + T1r[n] + b5S[n];
#pragma unroll
      for (int tt = 0; tt < NT; tt++) v += awS[m][tt] * LBS[tt][n];
      outp[orow + n] = fast_tanh(v);
    }
  }
}

// ---------------------------------------------------------------------------
// Generic f32 -> bf16 hi/lo split into the swizzled plane layout (fallback).
// ---------------------------------------------------------------------------
__global__ __launch_bounds__(256)
void prep_split(const float* __restrict__ src, int srcStride, int k0src, int K,
                u16* __restrict__ hi, u16* __restrict__ lo)
{
  const int r = blockIdx.x;
  const float* srow = src + (size_t)r*srcStride + k0src;
  for (int c = threadIdx.x; c < (K >> 3); c += 256) {
    int k0 = c * 8;
    union { u16 a[8]; short8v v; } ph, pl;
#pragma unroll
    for (int j = 0; j < 8; j++) {
      float v = srow[k0 + j];
      u16 h = f2bh(v);
      ph.a[j] = h;
      pl.a[j] = f2bh(v - bh2f(h));
    }
    size_t base = (size_t)r*K + (size_t)(k0 >> 5)*32 + swz_cb(k0, r)*8;
    *(short8v*)(hi + base) = ph.v;
    *(short8v*)(lo + base) = pl.v;
  }
}

__global__ __launch_bounds__(256)
void prep_split_pad(const float* __restrict__ src, int srcStride, int Ksrc, int Rsrc,
                    int K, u16* __restrict__ hi, u16* __restrict__ lo)
{
  const int r = blockIdx.x;
  const bool rok = r < Rsrc;
  const float* srow = src + (size_t)r*srcStride;
  for (int c = threadIdx.x; c < (K >> 3); c += 256) {
    int k0 = c * 8;
    union { u16 a[8]; short8v v; } ph, pl;
#pragma unroll
    for (int j = 0; j < 8; j++) {
      float v = (rok && (k0 + j) < Ksrc) ? srow[k0 + j] : 0.f;
      u16 h = f2bh(v);
      ph.a[j] = h;
      pl.a[j] = f2bh(v - bh2f(h));
    }
    size_t base = (size_t)r*K + (size_t)(k0 >> 5)*32 + swz_cb(k0, r)*8;
    *(short8v*)(hi + base) = ph.v;
    *(short8v*)(lo + base) = pl.v;
  }
}

// tier3: ALL independent input/weight splits in ONE launch.  grid (2048, 7).
__global__ __launch_bounds__(256)
void prep_weights(const float* __restrict__ W5, const float* __restrict__ W1,
                  const float* __restrict__ W2, const float* __restrict__ token,
                  const float* __restrict__ label,
                  u16* __restrict__ Wh,   u16* __restrict__ Wl,
                  u16* __restrict__ w1h,  u16* __restrict__ w1l,
                  u16* __restrict__ wb1h, u16* __restrict__ wb1l,
                  u16* __restrict__ wb2h, u16* __restrict__ wb2l,
                  u16* __restrict__ w2h,  u16* __restrict__ w2l,
                  u16* __restrict__ tokh, u16* __restrict__ tokl,
                  u16* __restrict__ labeh, u16* __restrict__ label_)
{
  const int job = blockIdx.y;
  const int r = blockIdx.x;
  const float* src; int stride, Ksrc, K, Rsrc, Rplane; u16 *hi, *lo;
  switch (job) {
    case 0: src = W5 + 1536; stride = 3072; Ksrc = 1536; K = KTOT; Rsrc = NH;  Rplane = NH;   hi = Wh;   lo = Wl;   break;
    case 1: src = W1;        stride = NH;   Ksrc = NH;   K = NH;   Rsrc = NH;  Rplane = NH;   hi = w1h;  lo = w1l;  break;
    case 2: src = W5;        stride = 3072; Ksrc = NH;   K = NH;   Rsrc = NH;  Rplane = NH;   hi = wb1h; lo = wb1l; break;
    case 3: src = W5 + NH;   stride = 3072; Ksrc = NH;   K = NH;   Rsrc = NH;  Rplane = NH;   hi = wb2h; lo = wb2l; break;
    case 4: src = W2;        stride = NE;   Ksrc = NE;   K = NEP;  Rsrc = NH;  Rplane = NH;   hi = w2h;  lo = w2l;  break;
    case 5: src = token;     stride = NH;   Ksrc = NH;   K = NH;   Rsrc = BS_; Rplane = BS_;  hi = tokh; lo = tokl; break;
    default: src = label;    stride = NE;   Ksrc = NE;   K = NEP;  Rsrc = NLT; Rplane = NLTP; hi = labeh; lo = label_; break;
  }
  if (r >= Rplane) return;
  const bool rok = r < Rsrc;
  const float* srow = src + (size_t)r*stride;
  for (int c = threadIdx.x; c < (K >> 3); c += 256) {
    int k0 = c * 8;
    union { u16 a[8]; short8v v; } ph, pl;
#pragma unroll
    for (int j = 0; j < 8; j++) {
      float v = (rok && (k0 + j) < Ksrc) ? srow[k0 + j] : 0.f;
      u16 h = f2bh(v);
      ph.a[j] = h;
      pl.a[j] = f2bh(v - bh2f(h));
    }
    size_t base = (size_t)r*K + (size_t)(k0 >> 5)*32 + swz_cb(k0, r)*8;
    *(short8v*)(hi + base) = ph.v;
    *(short8v*)(lo + base) = pl.v;
  }
}

// A' rows ordered [l][bs]:  A'[row][0:768) = tkn.*c2q,  [768:1536) = tkn.*q2c.
__global__ __launch_bounds__(256)
void aprep(const float* __restrict__ tkn, const float* __restrict__ lab,
           const float* __restrict__ aw, const float* __restrict__ q2c,
           u16* __restrict__ Ah, u16* __restrict__ Al)
{
  const int l   = blockIdx.x >> 4;
  const int bs0 = (blockIdx.x & 15) << 7;     // 128-row chunk, same b throughout
  const int b   = bs0 >> 8;
  const int t   = threadIdx.x;
  __shared__ float labS[NT][NH];
  __shared__ float q2cS[NH];
  __shared__ float awT[NT][128];
  for (int i = t; i < NT*NH; i += 256) { int tt = i / NH, k = i % NH; labS[tt][k] = lab[(size_t)(l*NT+tt)*NH + k]; }
  for (int i = t; i < NH; i += 256) q2cS[i] = q2c[(size_t)(b*NL + l)*NH + i];
  for (int i = t; i < NT*128; i += 256) { int tt = i >> 7, m = i & 127; awT[tt][m] = aw[(size_t)(bs0+m)*NLT + l*NT + tt]; }
  __syncthreads();

  for (int i = t; i < 128 * (NH/8); i += 256) {
    int m = i & 127, c = i >> 7;
    int k0 = c * 8;
    int bs = bs0 + m;
    const float* trow = tkn + (size_t)bs*NH + k0;
    float4 t4a = *(const float4*)(trow);
    float4 t4b = *(const float4*)(trow + 4);
    float tv[8] = {t4a.x, t4a.y, t4a.z, t4a.w, t4b.x, t4b.y, t4b.z, t4b.w};
    float awv[NT];
#pragma unroll
    for (int tt = 0; tt < NT; tt++) awv[tt] = awT[tt][m];

    union { u16 a[8]; short8v v; } h1, l1, h2, l2;
#pragma unroll
    for (int j = 0; j < 8; j++) {
      float cq = 0.f;
#pragma unroll
      for (int tt = 0; tt < NT; tt++) cq += awv[tt] * labS[tt][k0+j];
      float x1 = tv[j] * cq;
      float x2 = tv[j] * q2cS[k0+j];
      u16 h = f2bh(x1); h1.a[j] = h; l1.a[j] = f2bh(x1 - bh2f(h));
      u16 g = f2bh(x2); h2.a[j] = g; l2.a[j] = f2bh(x2 - bh2f(g));
    }
    size_t rowbase = ((size_t)l*BS_ + bs) * KTOT;
    size_t d1 = rowbase + (size_t)(k0 >> 5)*32 + swz_cb(k0, m)*8;
    size_t d2 = d1 + NH;
    *(short8v*)(Ah + d1) = h1.v;
    *(short8v*)(Al + d1) = l1.v;
    *(short8v*)(Ah + d2) = h2.v;
    *(short8v*)(Al + d2) = l2.v;
  }
}

// ---------------------------------------------------------------------------
// Plain 3-term MFMA GEMM, double-buffered (BK=32, 2x32KB LDS, counted vmcnt).
// C[m,n] = sum_k (Ah+Al)[m,k]*(Bh+Bl)[n,k].  Mv/Nv bound the f32 C-store.
// OUT=1: epilogue also emits bf16 hi/lo planes (rows m, k=n, plane-K = Kp,
// same swizzled layout as prep_split) — fuses the follow-up split pass.
// ---------------------------------------------------------------------------
template<int OUT>
__global__ __launch_bounds__(256)
void mfma_gemm_plainT(const u16* __restrict__ AhG, const u16* __restrict__ AlG,
                      const u16* __restrict__ BhG, const u16* __restrict__ BlG,
                      int K, float* __restrict__ C, int ldc, int Mv, int Nv,
                      u16* __restrict__ Ph, u16* __restrict__ Pl, int Kp)
{
  __shared__ __align__(16) char lds[65536];

  const int m0 = blockIdx.x * 128, n0 = blockIdx.y * 128;
  const int t = threadIdx.x;
  const int wv = t >> 6, lane = t & 63;
  const int wm0 = (wv >> 1) << 6;
  const int wn0 = (wv & 1) << 6;
  const int fr = lane & 15;
  const int g  = lane >> 4;
  const int r0 = wv*32 + (lane >> 2);
  const int cpos = (lane & 3) * 16;

  const size_t rowb = (size_t)K * 2;
  const char* gAh = (const char*)AhG + (size_t)m0 * rowb;
  const char* gAl = (const char*)AlG + (size_t)m0 * rowb;
  const char* gBh = (const char*)BhG + (size_t)n0 * rowb;
  const char* gBl = (const char*)BlG + (size_t)n0 * rowb;
  const size_t gs = 16 * rowb;

  f32x4 acc[4][4];
  f32x4 zz = {0.f, 0.f, 0.f, 0.f};
#pragma unroll
  for (int i = 0; i < 4; i++)
#pragma unroll
    for (int j = 0; j < 4; j++) acc[i][j] = zz;

  auto stage = [&](int kb, int half) {
    size_t ga = (size_t)r0 * rowb + (size_t)kb * 64 + cpos;
    char* base = lds + half*32768 + wv*2048;
    g2lds16(gAh + ga, base);           g2lds16(gAh + ga + gs, base + 1024);
    g2lds16(gAl + ga, base + 8192);    g2lds16(gAl + ga + gs, base + 9216);
    g2lds16(gBh + ga, base + 16384);   g2lds16(gBh + ga + gs, base + 17408);
    g2lds16(gBl + ga, base + 24576);   g2lds16(gBl + ga + gs, base + 25600);
  };

  const int nkb = K >> 5;
  stage(0, 0);
  for (int kb = 0; kb < nkb; kb++) {
    const int cur = kb & 1;
    if (kb + 1 < nkb) {
      stage(kb + 1, cur ^ 1);
      asm volatile("s_waitcnt vmcnt(8)" ::: "memory");
    } else {
      asm volatile("s_waitcnt vmcnt(0)" ::: "memory");
    }
    __builtin_amdgcn_s_barrier();
    __builtin_amdgcn_sched_barrier(0);

    const char* ldsAh = lds + cur*32768;
    const char* ldsAl = ldsAh + 8192;
    const char* ldsBh = ldsAh + 16384;
    const char* ldsBl = ldsAh + 24576;
    const int xk = ((g ^ ((fr >> 1) & 3)) << 4);
    short8v bh[4], bl[4];
#pragma unroll
    for (int j = 0; j < 4; j++) {
      int n = wn0 + j*16 + fr;
      bh[j] = *(const short8v*)(ldsBh + n*64 + xk);
      bl[j] = *(const short8v*)(ldsBl + n*64 + xk);
    }
    __builtin_amdgcn_s_setprio(1);
#pragma unroll
    for (int i = 0; i < 4; i++) {
      int m = wm0 + i*16 + fr;
      short8v ah = *(const short8v*)(ldsAh + m*64 + xk);
      short8v al = *(const short8v*)(ldsAl + m*64 + xk);
#pragma unroll
      for (int j = 0; j < 4; j++) {
        acc[i][j] = __builtin_amdgcn_mfma_f32_16x16x32_bf16(ah, bh[j], acc[i][j], 0, 0, 0);
        acc[i][j] = __builtin_amdgcn_mfma_f32_16x16x32_bf16(ah, bl[j], acc[i][j], 0, 0, 0);
        acc[i][j] = __builtin_amdgcn_mfma_f32_16x16x32_bf16(al, bh[j], acc[i][j], 0, 0, 0);
      }
    }
    __builtin_amdgcn_s_setprio(0);
    __builtin_amdgcn_sched_barrier(0);
    __builtin_amdgcn_s_barrier();
  }

  const int lr4 = (lane >> 4) * 4;
#pragma unroll
  for (int i = 0; i < 4; i++) {
#pragma unroll
    for (int r = 0; r < 4; r++) {
      int m = m0 + wm0 + i*16 + lr4 + r;
      float* Cr = C + (size_t)m * ldc + n0;
#pragma unroll
      for (int j = 0; j < 4; j++) {
        int nl = wn0 + j*16 + fr;
        int n = n0 + nl;
        float v = acc[i][j][r];
        if (m < Mv && n < Nv) Cr[nl] = v;
        if constexpr (OUT == 1) {
          u16 h = f2bh(v);
          u16 lo2 = f2bh(v - bh2f(h));
          size_t po = (size_t)m*Kp + (size_t)((n >> 5) << 5)
                    + ((((n >> 3) & 3) ^ ((m >> 1) & 3)) << 3) + (n & 7);
          Ph[po] = h;
          Pl[po] = lo2;
        }
      }
    }
  }
}

// ---------------------------------------------------------------------------
// Fused MFMA GEMM + epilogue.  Double-buffered BK=32 (2x32KB), counted vmcnt,
// 3-term bf16, 128x128 tile, 4 waves.  (verified; unchanged)
// ---------------------------------------------------------------------------
__global__ __launch_bounds__(256)
void mfma_gemm(const u16* __restrict__ AhG, const u16* __restrict__ AlG,
               const u16* __restrict__ WhG, const u16* __restrict__ WlG,
               const float* __restrict__ T1, const float* __restrict__ LBt,
               const float* __restrict__ aw, const float* __restrict__ b5,
               float* __restrict__ outp)
{
  __shared__ __align__(16) char lds[65536];

  int id = blockIdx.x;
  int swz = (id & 7) * 240 + (id >> 3);
  const int nb  = swz % 6;
  const int mbk = swz / 6;
  const int l   = mbk >> 4;
  const int bs0 = (mbk & 15) << 7;
  const int o0  = nb << 7;

  const int t = threadIdx.x;
  const int wv = t >> 6, lane = t & 63;
  const int wm0 = (wv >> 1) << 6;
  const int wn0 = (wv & 1) << 6;
  const int fr = lane & 15;
  const int g  = lane >> 4;
  const int r0 = wv*32 + (lane >> 2);
  const int cpos = (lane & 3) * 16;

  const char* gAh = (const char*)AhG + ((size_t)l*BS_ + bs0) * (KTOT*2);
  const char* gAl = (const char*)AlG + ((size_t)l*BS_ + bs0) * (KTOT*2);
  const char* gWh = (const char*)WhG + (size_t)o0 * (KTOT*2);
  const char* gWl = (const char*)WlG + (size_t)o0 * (KTOT*2);
  const size_t gs = 16 * (size_t)(KTOT*2);

  f32x4 acc[4][4];
  f32x4 zz = {0.f, 0.f, 0.f, 0.f};
#pragma unroll
  for (int i = 0; i < 4; i++)
#pragma unroll
    for (int j = 0; j < 4; j++) acc[i][j] = zz;

  auto stage = [&](int kb, int half) {
    size_t ga = (size_t)r0 * (KTOT*2) + (size_t)kb * 64 + cpos;
    char* base = lds + half*32768 + wv*2048;
    g2lds16(gAh + ga, base);           g2lds16(gAh + ga + gs, base + 1024);
    g2lds16(gAl + ga, base + 8192);    g2lds16(gAl + ga + gs, base + 9216);
    g2lds16(gWh + ga, base + 16384);   g2lds16(gWh + ga + gs, base + 17408);
    g2lds16(gWl + ga, base + 24576);   g2lds16(gWl + ga + gs, base + 25600);
  };

  const int nkb = KTOT/32;
  stage(0, 0);
  for (int kb = 0; kb < nkb; kb++) {
    const int cur = kb & 1;
    if (kb + 1 < nkb) {
      stage(kb + 1, cur ^ 1);
      asm volatile("s_waitcnt vmcnt(8)" ::: "memory");
    } else {
      asm volatile("s_waitcnt vmcnt(0)" ::: "memory");
    }
    __builtin_amdgcn_s_barrier();
    __builtin_amdgcn_sched_barrier(0);

    const char* ldsAh = lds + cur*32768;
    const char* ldsAl = ldsAh + 8192;
    const char* ldsWh = ldsAh + 16384;
    const char* ldsWl = ldsAh + 24576;
    const int xk = ((g ^ ((fr >> 1) & 3)) << 4);
    short8v wh[4], wl[4];
#pragma unroll
    for (int j = 0; j < 4; j++) {
      int n = wn0 + j*16 + fr;
      wh[j] = *(const short8v*)(ldsWh + n*64 + xk);
      wl[j] = *(const short8v*)(ldsWl + n*64 + xk);
    }
    __builtin_amdgcn_s_setprio(1);
#pragma unroll
    for (int i = 0; i < 4; i++) {
      int m = wm0 + i*16 + fr;
      short8v ah = *(const short8v*)(ldsAh + m*64 + xk);
      short8v al = *(const short8v*)(ldsAl + m*64 + xk);
#pragma unroll
      for (int j = 0; j < 4; j++) {
        acc[i][j] = __builtin_amdgcn_mfma_f32_16x16x32_bf16(ah, wh[j], acc[i][j], 0, 0, 0);
        acc[i][j] = __builtin_amdgcn_mfma_f32_16x16x32_bf16(ah, wl[j], acc[i][j], 0, 0, 0);
        acc[i][j] = __builtin_amdgcn_mfma_f32_16x16x32_bf16(al, wh[j], acc[i][j], 0, 0, 0);
      }
    }
    __builtin_amdgcn_s_setprio(0);
    __builtin_amdgcn_sched_barrier(0);
    __builtin_amdgcn_s_barrier();
  }

  float* LBs = (float*)lds;               // [8][128]
  float* aws = (float*)(lds + 4096);      // [128][8]
  float* b5s = (float*)(lds + 8192);      // [128]
  for (int i = t; i < NT*128; i += 256) { int tt = i >> 7, n = i & 127; LBs[i] = LBt[(size_t)(l*NT+tt)*NH + o0 + n]; }
  for (int i = t; i < 128*NT; i += 256) { int m = i >> 3, tt = i & 7; aws[i] = aw[(size_t)(bs0+m)*NLT + l*NT + tt]; }
  if (t < 128) b5s[t] = b5[o0 + t];
  __syncthreads();

  const int lr4 = (lane >> 4) * 4;
#pragma unroll
  for (int i = 0; i < 4; i++) {
#pragma unroll
    for (int r = 0; r < 4; r++) {
      int m = wm0 + i*16 + lr4 + r;
      int bs = bs0 + m;
      const float* T1r = T1 + (size_t)bs*NH + o0;
      size_t orow = ((size_t)bs*NL + l)*NH + o0;
      float awv[NT];
#pragma unroll
      for (int tt = 0; tt < NT; tt++) awv[tt] = aws[m*8 + tt];
#pragma unroll
      for (int j = 0; j < 4; j++) {
        int n = wn0 + j*16 + fr;
        float v = acc[i][j][r] + T1r[n] + b5s[n];
#pragma unroll
        for (int tt = 0; tt < NT; tt++) v += awv[tt] * LBs[tt*128 + n];
        outp[orow + n] = fast_tanh(v);
      }
    }
  }
}

extern "C" void kernel_launch(void* const* d_in, const int* in_sizes, int n_in,
                              void* d_out, int out_size, void* d_ws, size_t ws_size,
                              hipStream_t stream)
{
  const float* token = (const float*)d_in[0];
  const float* label = (const float*)d_in[1];
  const float* imask = (const float*)d_in[2];
  const float* lmask = (const float*)d_in[3];
  const float* W1    = (const float*)d_in[4];
  const float* W2    = (const float*)d_in[5];
  const float* W5    = (const float*)d_in[6];
  const float* b5    = (const float*)d_in[7];
  float* outp = (float*)d_out;

  // ---- workspace layout ----
  char* p = (char*)d_ws;
  float* tkn  = (float*)p; p += (size_t)BS_*NH*4;
  float* T1   = (float*)p; p += (size_t)BS_*NH*4;
  float* lab  = (float*)p; p += (size_t)NLT*NH*4;
  float* LB   = (float*)p; p += (size_t)NLT*NH*4;
  float* aw   = (float*)p; p += (size_t)BS_*NLT*4;
  float* b_in = (float*)p; p += (size_t)BS_*NL*4;
  float* bc   = (float*)p; p += (size_t)BS_*NL*4;
  float* q2c  = (float*)p; p += (size_t)NL*NB*NH*4;

  size_t baseBytes = (size_t)(p - (char*)d_ws);
  const size_t needA = (size_t)NL * BS_ * KTOT * 2;   // 125,829,120 each
  const size_t needW = (size_t)NH * KTOT * 2;         //   2,359,296 each
  bool tier1 = ws_size >= baseBytes + 2*needA + 2*needW;
  u16 *AhG = 0, *AlG = 0, *WhG = 0, *WlG = 0;
  if (tier1) {
    AhG = (u16*)p; p += needA;
    AlG = (u16*)p; p += needA;
    WhG = (u16*)p; p += needW;
    WlG = (u16*)p; p += needW;
  }
  // tier2: bf16 planes for the two pre-GEMMs
  const size_t szTok = (size_t)BS_*NH*2;   // 3,145,728
  const size_t szW   = (size_t)NH*NH*2;    // 1,179,648
  size_t extra2 = 2*szTok*2 + 2*szW*2;
  bool tier2 = tier1 && (ws_size >= (size_t)(p - (char*)d_ws) + extra2);
  u16 *tokh=0,*tokl=0,*w1h=0,*w1l=0,*wb1h=0,*wb1l=0,*tknh=0,*tknl=0;
  if (tier2) {
    tokh = (u16*)p; p += szTok;  tokl = (u16*)p; p += szTok;
    w1h  = (u16*)p; p += szW;    w1l  = (u16*)p; p += szW;
    wb1h = (u16*)p; p += szW;    wb1l = (u16*)p; p += szW;
    tknh = (u16*)p; p += szTok;  tknl = (u16*)p; p += szTok;
  }
  // tier3: lab/scores/LB on MFMA (padded planes)
  const size_t szWb2   = (size_t)NH*NH*2;        // 1,179,648
  const size_t szW2P   = (size_t)NH*NEP*2;       //   491,520
  const size_t szLabel = (size_t)NLTP*NEP*2;     //   163,840
  const size_t szLabP  = (size_t)NLTP*NH*2;      //   393,216
  const size_t szSc    = (size_t)BS_*NLT*4;      // 1,310,720
  size_t extra3 = 2*szWb2 + 2*szW2P + 2*szLabel + 2*szLabP + szSc;
  bool tier3 = tier2 && (ws_size >= (size_t)(p - (char*)d_ws) + extra3);
  u16 *wb2h=0,*wb2l=0,*w2h=0,*w2l=0,*labeh=0,*label_=0,*labh=0,*labl=0;
  float* sc = 0;
  if (tier3) {
    wb2h = (u16*)p; p += szWb2;   wb2l = (u16*)p; p += szWb2;
    w2h  = (u16*)p; p += szW2P;   w2l  = (u16*)p; p += szW2P;
    labeh= (u16*)p; p += szLabel; label_=(u16*)p; p += szLabel;
    labh = (u16*)p; p += szLabP;  labl = (u16*)p; p += szLabP;
    sc   = (float*)p; p += szSc;
  }

  if (tier3) {
    // one launch: all input/weight splits (7 jobs, fully parallel)
    prep_weights<<<dim3(BS_, 7), 256, 0, stream>>>(
        W5, W1, W2, token, label,
        WhG, WlG, w1h, w1l, wb1h, wb1l, wb2h, wb2l,
        w2h, w2l, tokh, tokl, labeh, label_);
    // tkn = token @ W1^T   (+ fused tknh/tknl planes)
    mfma_gemm_plainT<1><<<dim3(BS_/128, NH/128), 256, 0, stream>>>(
        tokh, tokl, w1h, w1l, NH, tkn, NH, BS_, NH, tknh, tknl, NH);
    // T1 = tkn @ W5b1^T
    mfma_gemm_plainT<0><<<dim3(BS_/128, NH/128), 256, 0, stream>>>(
        tknh, tknl, wb1h, wb1l, NH, T1, NH, BS_, NH, 0, 0, 0);
    // lab = label @ W2^T  (+ fused labh/labl planes; pad rows are zero)
    mfma_gemm_plainT<1><<<dim3(NLTP/128, NH/128), 256, 0, stream>>>(
        labeh, label_, w2h, w2l, NEP, lab, NH, NLT, NH, labh, labl, NH);
    // sc = tkn @ lab^T
    mfma_gemm_plainT<0><<<dim3(BS_/128, NLTP/128), 256, 0, stream>>>(
        tknh, tknl, labh, labl, NH, sc, NLT, BS_, NLT, 0, 0, 0);
    // LB = lab @ W5b2^T
    mfma_gemm_plainT<0><<<dim3(NLTP/128, NH/128), 256, 0, stream>>>(
        labh, labl, wb2h, wb2l, NH, LB, NH, NLT, NH, 0, 0, 0);
    aw_kernel<<<BS_, 256, 0, stream>>>(sc, lmask, imask, aw, b_in);
  } else {
    if (tier1)
      prep_split<<<NH, 256, 0, stream>>>(W5, 3072, 1536, KTOT, WhG, WlG);
    if (tier2) {
      prep_split<<<BS_, 256, 0, stream>>>(token, NH, 0, NH, tokh, tokl);
      prep_split<<<NH,  256, 0, stream>>>(W1,    NH, 0, NH, w1h,  w1l);
      prep_split<<<NH,  256, 0, stream>>>(W5,  3072, 0, NH, wb1h, wb1l);
      mfma_gemm_plainT<0><<<dim3(BS_/128, NH/128), 256, 0, stream>>>(
          tokh, tokl, w1h, w1l, NH, tkn, NH, BS_, NH, 0, 0, 0);
      prep_split<<<BS_, 256, 0, stream>>>(tkn, NH, 0, NH, tknh, tknl);
      mfma_gemm_plainT<0><<<dim3(BS_/128, NH/128), 256, 0, stream>>>(
          tknh, tknl, wb1h, wb1l, NH, T1, NH, BS_, NH, 0, 0, 0);
    } else {
      gemm64<<<dim3(BS_/64, NH/64), 256, 0, stream>>>(token, NH, W1, NH, NH, tkn, NH);
      gemm64<<<dim3(BS_/64, NH/64), 256, 0, stream>>>(tkn, NH, W5, 3072, NH, T1, NH);
    }
    lab_kernel<<<NLT, 256, 0, stream>>>(label, W2, lab);
    LB_kernel<<<NLT, 256, 0, stream>>>(lab, W5, LB);
    scores_kernel<<<BS_, 256, 0, stream>>>(tkn, lab, lmask, imask, aw, b_in);
  }

  softs_kernel<<<NB*NL, 256, 0, stream>>>(b_in, bc);
  q2c_kernel2<<<dim3(NB, NH/128), 256, 0, stream>>>(bc, tkn, q2c);

  if (tier1) {
    aprep<<<NL*16, 256, 0, stream>>>(tkn, lab, aw, q2c, AhG, AlG);
    mfma_gemm<<<NL*16*6, 256, 0, stream>>>(AhG, AlG, WhG, WlG, T1, LB, aw, b5, outp);
  } else {
    fused_out<<<dim3(NB*NL*4, NH/64), 256, 0, stream>>>(tkn, lab, aw, q2c, T1, LB, W5, b5, outp);
  }
}

// Round 6
// 674.044 us; speedup vs baseline: 1.2280x; 1.2280x over previous
//
#include <hip/hip_runtime.h>
#include <math.h>
#include <stdint.h>

#define NB 8
#define NS 256
#define NH 768
#define NL 20
#define NT 8
#define NE 300
#define NEGV (-10000.0f)
#define BS_ (NB*NS)          // 2048
#define NLT (NL*NT)          // 160
#define KTOT 1536            // [A1 | A2] concat K for the fused MFMA GEMM
#define NEP 320              // NE padded to mult of 32
#define NLTP 256             // NLT padded to mult of 128

typedef unsigned short u16;
typedef unsigned int   u32;
using short8v = __attribute__((ext_vector_type(8))) short;   // 8 bf16 = 4 VGPR
using f32x4   = __attribute__((ext_vector_type(4))) float;   // MFMA acc

__device__ __forceinline__ float fast_tanh(float x) {
  float e = __expf(2.0f * x);
  return 1.0f - 2.0f / (e + 1.0f);
}
// f32 -> bf16 round-to-nearest-even (bits)
__device__ __forceinline__ u16 f2bh(float f) {
  u32 u = __float_as_uint(f);
  return (u16)((u + 0x7fffu + ((u >> 16) & 1u)) >> 16);
}
__device__ __forceinline__ float bh2f(u16 h) {
  return __uint_as_float(((u32)h) << 16);
}
// async global->LDS, 16B per lane; lds ptr must be wave-uniform base
__device__ __forceinline__ void g2lds16(const void* g, void* s) {
  __builtin_amdgcn_global_load_lds((const __attribute__((address_space(1))) void*)g,
                                   (__attribute__((address_space(3))) void*)s, 16, 0, 0);
}
// Swizzle convention (ALL plane writers/readers): planes are row-major rows of
// K bf16.  Within each 64B k-block (32 values), the 16B chunk holding logical
// chunk c (c=0..3) is stored at position c ^ ((row>>1)&3).
__device__ __forceinline__ int swz_cb(int k0, int row) {
  return ((k0 >> 3) & 3) ^ ((row >> 1) & 3);
}

// ---------------------------------------------------------------------------
// f32 GEMM fallback (tier <2): C[m,n] = sum_k A[m,k]*B[n,k]
// ---------------------------------------------------------------------------
__global__ __launch_bounds__(256)
void gemm64(const float* __restrict__ A, int lda,
            const float* __restrict__ B, int ldb, int K,
            float* __restrict__ C, int ldc)
{
  __shared__ float As[16][64];
  __shared__ float Bs[16][64];
  const int t  = threadIdx.x;
  const int bm = blockIdx.x * 64, bn = blockIdx.y * 64;
  const int tm = t & 15, tn = t >> 4;
  const int lr = t >> 2;
  const int lk = (t & 3) * 4;
  float acc[4][4];
#pragma unroll
  for (int r = 0; r < 4; r++)
#pragma unroll
    for (int c = 0; c < 4; c++) acc[r][c] = 0.f;

  for (int kt = 0; kt < K; kt += 16) {
    float4 a4 = *(const float4*)(A + (size_t)(bm + lr) * lda + kt + lk);
    float4 b4 = *(const float4*)(B + (size_t)(bn + lr) * ldb + kt + lk);
    As[lk+0][lr] = a4.x; As[lk+1][lr] = a4.y; As[lk+2][lr] = a4.z; As[lk+3][lr] = a4.w;
    Bs[lk+0][lr] = b4.x; Bs[lk+1][lr] = b4.y; Bs[lk+2][lr] = b4.z; Bs[lk+3][lr] = b4.w;
    __syncthreads();
#pragma unroll
    for (int k = 0; k < 16; k++) {
      float av[4], bv[4];
#pragma unroll
      for (int r = 0; r < 4; r++) av[r] = As[k][tm*4 + r];
#pragma unroll
      for (int c = 0; c < 4; c++) bv[c] = Bs[k][tn*4 + c];
#pragma unroll
      for (int r = 0; r < 4; r++)
#pragma unroll
        for (int c = 0; c < 4; c++) acc[r][c] += av[r] * bv[c];
    }
    __syncthreads();
  }
#pragma unroll
  for (int r = 0; r < 4; r++)
#pragma unroll
    for (int c = 0; c < 4; c++)
      C[(size_t)(bm + tm*4 + r) * ldc + bn + tn*4 + c] = acc[r][c];
}

// ---- fallback small kernels (tier <3) ----
__global__ __launch_bounds__(256)
void lab_kernel(const float* __restrict__ label, const float* __restrict__ W2,
                float* __restrict__ lab)
{
  int lt = blockIdx.x;
  __shared__ __align__(16) float le[NE];
  for (int e = threadIdx.x; e < NE; e += 256) le[e] = label[(size_t)lt*NE + e];
  __syncthreads();
  for (int o = threadIdx.x; o < NH; o += 256) {
    const float4* wr = (const float4*)(W2 + (size_t)o*NE);
    const float4* l4 = (const float4*)le;
    float s = 0.f;
    for (int e = 0; e < NE/4; e++) {
      float4 a = l4[e], b = wr[e];
      s += a.x*b.x + a.y*b.y + a.z*b.z + a.w*b.w;
    }
    lab[(size_t)lt*NH + o] = s;
  }
}

__global__ __launch_bounds__(256)
void LB_kernel(const float* __restrict__ lab, const float* __restrict__ W5,
               float* __restrict__ LB)
{
  int lt = blockIdx.x;
  __shared__ __align__(16) float lr[NH];
  for (int h = threadIdx.x; h < NH; h += 256) lr[h] = lab[(size_t)lt*NH + h];
  __syncthreads();
  for (int o = threadIdx.x; o < NH; o += 256) {
    const float4* wr = (const float4*)(W5 + (size_t)o*3072 + NH);
    const float4* l4 = (const float4*)lr;
    float s = 0.f;
    for (int h = 0; h < NH/4; h++) {
      float4 a = l4[h], b = wr[h];
      s += a.x*b.x + a.y*b.y + a.z*b.z + a.w*b.w;
    }
    LB[(size_t)lt*NH + o] = s;
  }
}

__global__ __launch_bounds__(256)
void scores_kernel(const float* __restrict__ tkn, const float* __restrict__ lab,
                   const float* __restrict__ lmask, const float* __restrict__ imask,
                   float* __restrict__ aw, float* __restrict__ b_in)
{
  int bs = blockIdx.x;
  __shared__ __align__(16) float trow[NH];
  __shared__ float sc[NLT];
  __shared__ float mL[NL], iL[NL];
  for (int h = threadIdx.x; h < NH; h += 256) trow[h] = tkn[(size_t)bs*NH + h];
  __syncthreads();
  int j = threadIdx.x;
  if (j < NLT) {
    const float4* lrow = (const float4*)(lab + (size_t)j*NH);
    const float4* t4   = (const float4*)trow;
    float s = 0.f;
    for (int h = 0; h < NH/4; h++) {
      float4 a = t4[h], b = lrow[h];
      s += a.x*b.x + a.y*b.y + a.z*b.z + a.w*b.w;
    }
    s += (1.0f - lmask[j]) * NEGV;
    sc[j] = s;
  }
  __syncthreads();
  if (j < NL) {
    float m = sc[j*8];
    for (int t = 1; t < 8; t++) m = fmaxf(m, sc[j*8 + t]);
    float ssum = 0.f;
    for (int t = 0; t < 8; t++) ssum += __expf(sc[j*8 + t] - m);
    mL[j] = m; iL[j] = 1.0f / ssum;
    b_in[(size_t)bs*NL + j] = m + (1.0f - imask[bs]) * NEGV;
  }
  __syncthreads();
  if (j < NLT) aw[(size_t)bs*NLT + j] = __expf(sc[j] - mL[j >> 3]) * iL[j >> 3];
}

// tier3: softmax/aw from precomputed sc[BS_, NLT]
__global__ __launch_bounds__(256)
void aw_kernel(const float* __restrict__ sc_in, const float* __restrict__ lmask,
               const float* __restrict__ imask, float* __restrict__ aw,
               float* __restrict__ b_in)
{
  int bs = blockIdx.x;
  __shared__ float sc[NLT];
  __shared__ float mL[NL], iL[NL];
  int j = threadIdx.x;
  if (j < NLT) sc[j] = sc_in[(size_t)bs*NLT + j] + (1.0f - lmask[j]) * NEGV;
  __syncthreads();
  if (j < NL) {
    float m = sc[j*8];
    for (int t = 1; t < 8; t++) m = fmaxf(m, sc[j*8 + t]);
    float ssum = 0.f;
    for (int t = 0; t < 8; t++) ssum += __expf(sc[j*8 + t] - m);
    mL[j] = m; iL[j] = 1.0f / ssum;
    b_in[(size_t)bs*NL + j] = m + (1.0f - imask[bs]) * NEGV;
  }
  __syncthreads();
  if (j < NLT) aw[(size_t)bs*NLT + j] = __expf(sc[j] - mL[j >> 3]) * iL[j >> 3];
}

__global__ __launch_bounds__(256)
void softs_kernel(const float* __restrict__ b_in, float* __restrict__ bc)
{
  int b = blockIdx.x / NL, l = blockIdx.x % NL;
  int s = threadIdx.x;
  __shared__ float red[256];
  float v = b_in[((size_t)b*NS + s)*NL + l];
  red[s] = v; __syncthreads();
  for (int off = 128; off > 0; off >>= 1) {
    if (s < off) red[s] = fmaxf(red[s], red[s + off]);
    __syncthreads();
  }
  float m = red[0]; __syncthreads();
  float e = __expf(v - m);
  red[s] = e; __syncthreads();
  for (int off = 128; off > 0; off >>= 1) {
    if (s < off) red[s] += red[s + off];
    __syncthreads();
  }
  bc[((size_t)b*NS + s)*NL + l] = e / red[0];
}

// q2c[b,l,h] = sum_s bc[b,s,l]*tkn[b,s,h].  Grid (NB, NH/128): each block
// reads its tkn h-slice ONCE.
__global__ __launch_bounds__(256)
void q2c_kernel2(const float* __restrict__ bc, const float* __restrict__ tkn,
                 float* __restrict__ q2c)
{
  const int b  = blockIdx.x;
  const int h0 = blockIdx.y * 128;
  const int t  = threadIdx.x;
  const int th = t & 127, half = t >> 7;
  __shared__ __align__(16) float bcS[NS*NL];        // 20 KB
  __shared__ __align__(16) float4 part[2*5*128];    // 20 KB
  for (int i = t; i < NS*NL; i += 256) bcS[i] = bc[(size_t)b*NS*NL + i];
  __syncthreads();
  float4 acc[5];
#pragma unroll
  for (int g = 0; g < 5; g++) acc[g] = {0.f, 0.f, 0.f, 0.f};
  const int h = h0 + th;
  for (int s = half*128; s < half*128 + 128; s++) {
    float tv = tkn[((size_t)b*NS + s)*NH + h];
    const float4* bl4 = (const float4*)(bcS + s*NL);
#pragma unroll
    for (int g = 0; g < 5; g++) {
      float4 w = bl4[g];
      acc[g].x += w.x*tv; acc[g].y += w.y*tv; acc[g].z += w.z*tv; acc[g].w += w.w*tv;
    }
  }
#pragma unroll
  for (int g = 0; g < 5; g++) part[(half*5 + g)*128 + th] = acc[g];
  __syncthreads();
  if (half == 0) {
#pragma unroll
    for (int g = 0; g < 5; g++) {
      float4 a = part[g*128 + th], c = part[(5 + g)*128 + th];
#pragma unroll
      for (int cc = 0; cc < 4; cc++) {
        int l = g*4 + cc;
        float v = ((const float*)&a)[cc] + ((const float*)&c)[cc];
        q2c[((size_t)(b*NL + l))*NH + h] = v;
      }
    }
  }
}

// ---------------------------------------------------------------------------
// OLD fused_out — fallback when ws can't even hold the fused-GEMM planes.
// ---------------------------------------------------------------------------
__global__ __launch_bounds__(256)
void fused_out(const float* __restrict__ tkn, const float* __restrict__ lab,
               const float* __restrict__ aw, const float* __restrict__ q2c,
               const float* __restrict__ T1, const float* __restrict__ LB,
               const float* __restrict__ W5, const float* __restrict__ b5,
               float* __restrict__ outp)
{
  const int t  = threadIdx.x;
  const int sq = blockIdx.x & 3;
  const int l  = (blockIdx.x >> 2) % NL;
  const int b  = blockIdx.x / (4 * NL);
  const int o0 = blockIdx.y * 64;
  const int s0 = sq * 64;
  const int tm = t & 15, tn = t >> 4;
  const int lr = t >> 2;
  const int lk = (t & 3) * 4;

  __shared__ float A1s[16][64];
  __shared__ float A2s[16][64];
  __shared__ float Cs[16][64];
  __shared__ float Ds[16][64];
  __shared__ float labS[NT][16];
  __shared__ float q2cS[16];
  __shared__ float awS[64][NT];
  __shared__ float LBS[NT][64];
  __shared__ float b5S[64];

  for (int i = t; i < 64*NT; i += 256) {
    int m = i >> 3, tt = i & 7;
    awS[m][tt] = aw[(size_t)(b*NS + s0 + m) * NLT + l*NT + tt];
  }
  for (int i = t; i < NT*64; i += 256) {
    int tt = i >> 6, n = i & 63;
    LBS[tt][n] = LB[(size_t)(l*NT + tt) * NH + o0 + n];
  }
  if (t < 64) b5S[t] = b5[o0 + t];

  float acc[4][4];
#pragma unroll
  for (int r = 0; r < 4; r++)
#pragma unroll
    for (int c = 0; c < 4; c++) acc[r][c] = 0.f;

  for (int kt = 0; kt < NH; kt += 16) {
    if (t < 128) { int tt = t >> 4, k = t & 15; labS[tt][k] = lab[(size_t)(l*NT + tt)*NH + kt + k]; }
    if (t < 16)  q2cS[t] = q2c[(size_t)(b*NL + l)*NH + kt + t];
    {
      float4 c4 = *(const float4*)(W5 + (size_t)(o0 + lr)*3072 + 1536 + kt + lk);
      Cs[lk+0][lr] = c4.x; Cs[lk+1][lr] = c4.y; Cs[lk+2][lr] = c4.z; Cs[lk+3][lr] = c4.w;
      float4 d4 = *(const float4*)(W5 + (size_t)(o0 + lr)*3072 + 2304 + kt + lk);
      Ds[lk+0][lr] = d4.x; Ds[lk+1][lr] = d4.y; Ds[lk+2][lr] = d4.z; Ds[lk+3][lr] = d4.w;
    }
    __syncthreads();
    {
      float4 t4 = *(const float4*)(tkn + (size_t)(b*NS + s0 + lr)*NH + kt + lk);
      float tv[4] = {t4.x, t4.y, t4.z, t4.w};
#pragma unroll
      for (int j = 0; j < 4; j++) {
        int k = lk + j;
        float c2 = 0.f;
#pragma unroll
        for (int tt = 0; tt < NT; tt++) c2 += awS[lr][tt] * labS[tt][k];
        A1s[k][lr] = tv[j] * c2;
        A2s[k][lr] = tv[j] * q2cS[k];
      }
    }
    __syncthreads();
#pragma unroll
    for (int k = 0; k < 16; k++) {
      float a1[4], a2[4], wc[4], wd[4];
#pragma unroll
      for (int r = 0; r < 4; r++) { a1[r] = A1s[k][tm*4 + r]; a2[r] = A2s[k][tm*4 + r]; }
#pragma unroll
      for (int c = 0; c < 4; c++) { wc[c] = Cs[k][tn*4 + c]; wd[c] = Ds[k][tn*4 + c]; }
#pragma unroll
      for (int r = 0; r < 4; r++)
#pragma unroll
        for (int c = 0; c < 4; c++)
          acc[r][c] += a1[r]*wc[c] + a2[r]*wd[c];
    }
    __syncthreads();
  }

#pragma unroll
  for (int r = 0; r < 4; r++) {
    int m = tm*4 + r;
    int s = s0 + m;
    size_t orow = ((size_t)(b*NS + s)*NL + l)*NH + o0;
    const float* T1r = T1 + (size_t)(b*NS + s)*NH + o0;
#pragma unroll
    for (int c = 0; c < 4; c++) {
      int n = tn*4 + c;
      float v = acc[r][c] + T1r[n] + b5S[n];
#pragma unroll
      for (int tt = 0; tt < NT; tt++) v += awS[m][tt] * LBS[tt][n];
      outp[orow + n] = fast_tanh(v);
    }
  }
}

// ---------------------------------------------------------------------------
// Generic f32 -> bf16 hi/lo split into the swizzled plane layout (fallback).
// ---------------------------------------------------------------------------
__global__ __launch_bounds__(256)
void prep_split(const float* __restrict__ src, int srcStride, int k0src, int K,
                u16* __restrict__ hi, u16* __restrict__ lo)
{
  const int r = blockIdx.x;
  const float* srow = src + (size_t)r*srcStride + k0src;
  for (int c = threadIdx.x; c < (K >> 3); c += 256) {
    int k0 = c * 8;
    union { u16 a[8]; short8v v; } ph, pl;
#pragma unroll
    for (int j = 0; j < 8; j++) {
      float v = srow[k0 + j];
      u16 h = f2bh(v);
      ph.a[j] = h;
      pl.a[j] = f2bh(v - bh2f(h));
    }
    size_t base = (size_t)r*K + (size_t)(k0 >> 5)*32 + swz_cb(k0, r)*8;
    *(short8v*)(hi + base) = ph.v;
    *(short8v*)(lo + base) = pl.v;
  }
}

__global__ __launch_bounds__(256)
void prep_split_pad(const float* __restrict__ src, int srcStride, int Ksrc, int Rsrc,
                    int K, u16* __restrict__ hi, u16* __restrict__ lo)
{
  const int r = blockIdx.x;
  const bool rok = r < Rsrc;
  const float* srow = src + (size_t)r*srcStride;
  for (int c = threadIdx.x; c < (K >> 3); c += 256) {
    int k0 = c * 8;
    union { u16 a[8]; short8v v; } ph, pl;
#pragma unroll
    for (int j = 0; j < 8; j++) {
      float v = (rok && (k0 + j) < Ksrc) ? srow[k0 + j] : 0.f;
      u16 h = f2bh(v);
      ph.a[j] = h;
      pl.a[j] = f2bh(v - bh2f(h));
    }
    size_t base = (size_t)r*K + (size_t)(k0 >> 5)*32 + swz_cb(k0, r)*8;
    *(short8v*)(hi + base) = ph.v;
    *(short8v*)(lo + base) = pl.v;
  }
}

// tier3: ALL independent input/weight splits in ONE launch.  grid (2048, 7).
__global__ __launch_bounds__(256)
void prep_weights(const float* __restrict__ W5, const float* __restrict__ W1,
                  const float* __restrict__ W2, const float* __restrict__ token,
                  const float* __restrict__ label,
                  u16* __restrict__ Wh,   u16* __restrict__ Wl,
                  u16* __restrict__ w1h,  u16* __restrict__ w1l,
                  u16* __restrict__ wb1h, u16* __restrict__ wb1l,
                  u16* __restrict__ wb2h, u16* __restrict__ wb2l,
                  u16* __restrict__ w2h,  u16* __restrict__ w2l,
                  u16* __restrict__ tokh, u16* __restrict__ tokl,
                  u16* __restrict__ labeh, u16* __restrict__ label_)
{
  const int job = blockIdx.y;
  const int r = blockIdx.x;
  const float* src; int stride, Ksrc, K, Rsrc, Rplane; u16 *hi, *lo;
  switch (job) {
    case 0: src = W5 + 1536; stride = 3072; Ksrc = 1536; K = KTOT; Rsrc = NH;  Rplane = NH;   hi = Wh;   lo = Wl;   break;
    case 1: src = W1;        stride = NH;   Ksrc = NH;   K = NH;   Rsrc = NH;  Rplane = NH;   hi = w1h;  lo = w1l;  break;
    case 2: src = W5;        stride = 3072; Ksrc = NH;   K = NH;   Rsrc = NH;  Rplane = NH;   hi = wb1h; lo = wb1l; break;
    case 3: src = W5 + NH;   stride = 3072; Ksrc = NH;   K = NH;   Rsrc = NH;  Rplane = NH;   hi = wb2h; lo = wb2l; break;
    case 4: src = W2;        stride = NE;   Ksrc = NE;   K = NEP;  Rsrc = NH;  Rplane = NH;   hi = w2h;  lo = w2l;  break;
    case 5: src = token;     stride = NH;   Ksrc = NH;   K = NH;   Rsrc = BS_; Rplane = BS_;  hi = tokh; lo = tokl; break;
    default: src = label;    stride = NE;   Ksrc = NE;   K = NEP;  Rsrc = NLT; Rplane = NLTP; hi = labeh; lo = label_; break;
  }
  if (r >= Rplane) return;
  const bool rok = r < Rsrc;
  const float* srow = src + (size_t)r*stride;
  for (int c = threadIdx.x; c < (K >> 3); c += 256) {
    int k0 = c * 8;
    union { u16 a[8]; short8v v; } ph, pl;
#pragma unroll
    for (int j = 0; j < 8; j++) {
      float v = (rok && (k0 + j) < Ksrc) ? srow[k0 + j] : 0.f;
      u16 h = f2bh(v);
      ph.a[j] = h;
      pl.a[j] = f2bh(v - bh2f(h));
    }
    size_t base = (size_t)r*K + (size_t)(k0 >> 5)*32 + swz_cb(k0, r)*8;
    *(short8v*)(hi + base) = ph.v;
    *(short8v*)(lo + base) = pl.v;
  }
}

// A' rows ordered [l][bs]:  A'[row][0:768) = tkn.*c2q,  [768:1536) = tkn.*q2c.
// ROUND-6 FIX: wave-tile [4 rows x 16 chunks] — 16 consecutive lanes cover a
// 256B contiguous run of ONE plane row (coalesced stores + tkn loads), vs the
// old m-fastest mapping whose every 16B store hit a different 3KB-distant row.
// labS reads drop from broadcast to 4-way bank alias (cheap, ~1.6x on LDS).
__global__ __launch_bounds__(256)
void aprep(const float* __restrict__ tkn, const float* __restrict__ lab,
           const float* __restrict__ aw, const float* __restrict__ q2c,
           u16* __restrict__ Ah, u16* __restrict__ Al)
{
  const int l   = blockIdx.x >> 4;
  const int bs0 = (blockIdx.x & 15) << 7;     // 128-row chunk, same b throughout
  const int b   = bs0 >> 8;
  const int t   = threadIdx.x;
  __shared__ float labS[NT][NH];
  __shared__ float q2cS[NH];
  __shared__ float awT[NT][128];
  for (int i = t; i < NT*NH; i += 256) { int tt = i / NH, k = i % NH; labS[tt][k] = lab[(size_t)(l*NT+tt)*NH + k]; }
  for (int i = t; i < NH; i += 256) q2cS[i] = q2c[(size_t)(b*NL + l)*NH + i];
  for (int i = t; i < NT*128; i += 256) { int tt = i >> 7, m = i & 127; awT[tt][m] = aw[(size_t)(bs0+m)*NLT + l*NT + tt]; }
  __syncthreads();

  const int w    = t >> 6;        // wave 0..3
  const int l6   = t & 63;
  const int mloc = l6 >> 4;       // 0..3   (row within wave tile)
  const int c16  = l6 & 15;       // 0..15  (chunk within wave tile)

  // 128 rows x 96 chunks = 48 iterations of [16 rows x 16 chunks] per block
  for (int ii = 0; ii < 48; ii++) {
    const int ct = ii % 6, rt = ii / 6;
    const int m  = rt*16 + w*4 + mloc;
    const int c  = ct*16 + c16;
    const int k0 = c * 8;
    const int bs = bs0 + m;
    const float* trow = tkn + (size_t)bs*NH + k0;
    float4 t4a = *(const float4*)(trow);
    float4 t4b = *(const float4*)(trow + 4);
    float tv[8] = {t4a.x, t4a.y, t4a.z, t4a.w, t4b.x, t4b.y, t4b.z, t4b.w};
    float awv[NT];
#pragma unroll
    for (int tt = 0; tt < NT; tt++) awv[tt] = awT[tt][m];

    union { u16 a[8]; short8v v; } h1, l1, h2, l2;
#pragma unroll
    for (int j = 0; j < 8; j++) {
      float cq = 0.f;
#pragma unroll
      for (int tt = 0; tt < NT; tt++) cq += awv[tt] * labS[tt][k0+j];
      float x1 = tv[j] * cq;
      float x2 = tv[j] * q2cS[k0+j];
      u16 h = f2bh(x1); h1.a[j] = h; l1.a[j] = f2bh(x1 - bh2f(h));
      u16 g = f2bh(x2); h2.a[j] = g; l2.a[j] = f2bh(x2 - bh2f(g));
    }
    // plane row = l*BS_ + bs; (row>>1)&3 == (m>>1)&3 since l*BS_+bs0 % 8 == 0
    size_t rowbase = ((size_t)l*BS_ + bs) * KTOT;
    size_t d1 = rowbase + (size_t)(k0 >> 5)*32 + swz_cb(k0, m)*8;
    size_t d2 = d1 + NH;
    *(short8v*)(Ah + d1) = h1.v;
    *(short8v*)(Al + d1) = l1.v;
    *(short8v*)(Ah + d2) = h2.v;
    *(short8v*)(Al + d2) = l2.v;
  }
}

// ---------------------------------------------------------------------------
// Plain 3-term MFMA GEMM, double-buffered (BK=32, 2x32KB LDS, counted vmcnt).
// C[m,n] = sum_k (Ah+Al)[m,k]*(Bh+Bl)[n,k].  Mv/Nv bound the f32 C-store.
// OUT=1: epilogue also emits bf16 hi/lo planes (fuses the follow-up split).
// ---------------------------------------------------------------------------
template<int OUT>
__global__ __launch_bounds__(256)
void mfma_gemm_plainT(const u16* __restrict__ AhG, const u16* __restrict__ AlG,
                      const u16* __restrict__ BhG, const u16* __restrict__ BlG,
                      int K, float* __restrict__ C, int ldc, int Mv, int Nv,
                      u16* __restrict__ Ph, u16* __restrict__ Pl, int Kp)
{
  __shared__ __align__(16) char lds[65536];

  const int m0 = blockIdx.x * 128, n0 = blockIdx.y * 128;
  const int t = threadIdx.x;
  const int wv = t >> 6, lane = t & 63;
  const int wm0 = (wv >> 1) << 6;
  const int wn0 = (wv & 1) << 6;
  const int fr = lane & 15;
  const int g  = lane >> 4;
  const int r0 = wv*32 + (lane >> 2);
  const int cpos = (lane & 3) * 16;

  const size_t rowb = (size_t)K * 2;
  const char* gAh = (const char*)AhG + (size_t)m0 * rowb;
  const char* gAl = (const char*)AlG + (size_t)m0 * rowb;
  const char* gBh = (const char*)BhG + (size_t)n0 * rowb;
  const char* gBl = (const char*)BlG + (size_t)n0 * rowb;
  const size_t gs = 16 * rowb;

  f32x4 acc[4][4];
  f32x4 zz = {0.f, 0.f, 0.f, 0.f};
#pragma unroll
  for (int i = 0; i < 4; i++)
#pragma unroll
    for (int j = 0; j < 4; j++) acc[i][j] = zz;

  auto stage = [&](int kb, int half) {
    size_t ga = (size_t)r0 * rowb + (size_t)kb * 64 + cpos;
    char* base = lds + half*32768 + wv*2048;
    g2lds16(gAh + ga, base);           g2lds16(gAh + ga + gs, base + 1024);
    g2lds16(gAl + ga, base + 8192);    g2lds16(gAl + ga + gs, base + 9216);
    g2lds16(gBh + ga, base + 16384);   g2lds16(gBh + ga + gs, base + 17408);
    g2lds16(gBl + ga, base + 24576);   g2lds16(gBl + ga + gs, base + 25600);
  };

  const int nkb = K >> 5;
  stage(0, 0);
  for (int kb = 0; kb < nkb; kb++) {
    const int cur = kb & 1;
    if (kb + 1 < nkb) {
      stage(kb + 1, cur ^ 1);
      asm volatile("s_waitcnt vmcnt(8)" ::: "memory");
    } else {
      asm volatile("s_waitcnt vmcnt(0)" ::: "memory");
    }
    __builtin_amdgcn_s_barrier();
    __builtin_amdgcn_sched_barrier(0);

    const char* ldsAh = lds + cur*32768;
    const char* ldsAl = ldsAh + 8192;
    const char* ldsBh = ldsAh + 16384;
    const char* ldsBl = ldsAh + 24576;
    const int xk = ((g ^ ((fr >> 1) & 3)) << 4);
    short8v bh[4], bl[4];
#pragma unroll
    for (int j = 0; j < 4; j++) {
      int n = wn0 + j*16 + fr;
      bh[j] = *(const short8v*)(ldsBh + n*64 + xk);
      bl[j] = *(const short8v*)(ldsBl + n*64 + xk);
    }
    __builtin_amdgcn_s_setprio(1);
#pragma unroll
    for (int i = 0; i < 4; i++) {
      int m = wm0 + i*16 + fr;
      short8v ah = *(const short8v*)(ldsAh + m*64 + xk);
      short8v al = *(const short8v*)(ldsAl + m*64 + xk);
#pragma unroll
      for (int j = 0; j < 4; j++) {
        acc[i][j] = __builtin_amdgcn_mfma_f32_16x16x32_bf16(ah, bh[j], acc[i][j], 0, 0, 0);
        acc[i][j] = __builtin_amdgcn_mfma_f32_16x16x32_bf16(ah, bl[j], acc[i][j], 0, 0, 0);
        acc[i][j] = __builtin_amdgcn_mfma_f32_16x16x32_bf16(al, bh[j], acc[i][j], 0, 0, 0);
      }
    }
    __builtin_amdgcn_s_setprio(0);
    __builtin_amdgcn_sched_barrier(0);
    __builtin_amdgcn_s_barrier();
  }

  const int lr4 = (lane >> 4) * 4;
#pragma unroll
  for (int i = 0; i < 4; i++) {
#pragma unroll
    for (int r = 0; r < 4; r++) {
      int m = m0 + wm0 + i*16 + lr4 + r;
      float* Cr = C + (size_t)m * ldc + n0;
#pragma unroll
      for (int j = 0; j < 4; j++) {
        int nl = wn0 + j*16 + fr;
        int n = n0 + nl;
        float v = acc[i][j][r];
        if (m < Mv && n < Nv) Cr[nl] = v;
        if constexpr (OUT == 1) {
          u16 h = f2bh(v);
          u16 lo2 = f2bh(v - bh2f(h));
          size_t po = (size_t)m*Kp + (size_t)((n >> 5) << 5)
                    + ((((n >> 3) & 3) ^ ((m >> 1) & 3)) << 3) + (n & 7);
          Ph[po] = h;
          Pl[po] = lo2;
        }
      }
    }
  }
}

// ---------------------------------------------------------------------------
// Fused MFMA GEMM + epilogue.  Double-buffered BK=32 (2x32KB), counted vmcnt,
// 3-term bf16, 128x128 tile, 4 waves.  (verified; unchanged)
// ---------------------------------------------------------------------------
__global__ __launch_bounds__(256)
void mfma_gemm(const u16* __restrict__ AhG, const u16* __restrict__ AlG,
               const u16* __restrict__ WhG, const u16* __restrict__ WlG,
               const float* __restrict__ T1, const float* __restrict__ LBt,
               const float* __restrict__ aw, const float* __restrict__ b5,
               float* __restrict__ outp)
{
  __shared__ __align__(16) char lds[65536];

  int id = blockIdx.x;
  int swz = (id & 7) * 240 + (id >> 3);
  const int nb  = swz % 6;
  const int mbk = swz / 6;
  const int l   = mbk >> 4;
  const int bs0 = (mbk & 15) << 7;
  const int o0  = nb << 7;

  const int t = threadIdx.x;
  const int wv = t >> 6, lane = t & 63;
  const int wm0 = (wv >> 1) << 6;
  const int wn0 = (wv & 1) << 6;
  const int fr = lane & 15;
  const int g  = lane >> 4;
  const int r0 = wv*32 + (lane >> 2);
  const int cpos = (lane & 3) * 16;

  const char* gAh = (const char*)AhG + ((size_t)l*BS_ + bs0) * (KTOT*2);
  const char* gAl = (const char*)AlG + ((size_t)l*BS_ + bs0) * (KTOT*2);
  const char* gWh = (const char*)WhG + (size_t)o0 * (KTOT*2);
  const char* gWl = (const char*)WlG + (size_t)o0 * (KTOT*2);
  const size_t gs = 16 * (size_t)(KTOT*2);

  f32x4 acc[4][4];
  f32x4 zz = {0.f, 0.f, 0.f, 0.f};
#pragma unroll
  for (int i = 0; i < 4; i++)
#pragma unroll
    for (int j = 0; j < 4; j++) acc[i][j] = zz;

  auto stage = [&](int kb, int half) {
    size_t ga = (size_t)r0 * (KTOT*2) + (size_t)kb * 64 + cpos;
    char* base = lds + half*32768 + wv*2048;
    g2lds16(gAh + ga, base);           g2lds16(gAh + ga + gs, base + 1024);
    g2lds16(gAl + ga, base + 8192);    g2lds16(gAl + ga + gs, base + 9216);
    g2lds16(gWh + ga, base + 16384);   g2lds16(gWh + ga + gs, base + 17408);
    g2lds16(gWl + ga, base + 24576);   g2lds16(gWl + ga + gs, base + 25600);
  };

  const int nkb = KTOT/32;
  stage(0, 0);
  for (int kb = 0; kb < nkb; kb++) {
    const int cur = kb & 1;
    if (kb + 1 < nkb) {
      stage(kb + 1, cur ^ 1);
      asm volatile("s_waitcnt vmcnt(8)" ::: "memory");
    } else {
      asm volatile("s_waitcnt vmcnt(0)" ::: "memory");
    }
    __builtin_amdgcn_s_barrier();
    __builtin_amdgcn_sched_barrier(0);

    const char* ldsAh = lds + cur*32768;
    const char* ldsAl = ldsAh + 8192;
    const char* ldsWh = ldsAh + 16384;
    const char* ldsWl = ldsAh + 24576;
    const int xk = ((g ^ ((fr >> 1) & 3)) << 4);
    short8v wh[4], wl[4];
#pragma unroll
    for (int j = 0; j < 4; j++) {
      int n = wn0 + j*16 + fr;
      wh[j] = *(const short8v*)(ldsWh + n*64 + xk);
      wl[j] = *(const short8v*)(ldsWl + n*64 + xk);
    }
    __builtin_amdgcn_s_setprio(1);
#pragma unroll
    for (int i = 0; i < 4; i++) {
      int m = wm0 + i*16 + fr;
      short8v ah = *(const short8v*)(ldsAh + m*64 + xk);
      short8v al = *(const short8v*)(ldsAl + m*64 + xk);
#pragma unroll
      for (int j = 0; j < 4; j++) {
        acc[i][j] = __builtin_amdgcn_mfma_f32_16x16x32_bf16(ah, wh[j], acc[i][j], 0, 0, 0);
        acc[i][j] = __builtin_amdgcn_mfma_f32_16x16x32_bf16(ah, wl[j], acc[i][j], 0, 0, 0);
        acc[i][j] = __builtin_amdgcn_mfma_f32_16x16x32_bf16(al, wh[j], acc[i][j], 0, 0, 0);
      }
    }
    __builtin_amdgcn_s_setprio(0);
    __builtin_amdgcn_sched_barrier(0);
    __builtin_amdgcn_s_barrier();
  }

  float* LBs = (float*)lds;               // [8][128]
  float* aws = (float*)(lds + 4096);      // [128][8]
  float* b5s = (float*)(lds + 8192);      // [128]
  for (int i = t; i < NT*128; i += 256) { int tt = i >> 7, n = i & 127; LBs[i] = LBt[(size_t)(l*NT+tt)*NH + o0 + n]; }
  for (int i = t; i < 128*NT; i += 256) { int m = i >> 3, tt = i & 7; aws[i] = aw[(size_t)(bs0+m)*NLT + l*NT + tt]; }
  if (t < 128) b5s[t] = b5[o0 + t];
  __syncthreads();

  const int lr4 = (lane >> 4) * 4;
#pragma unroll
  for (int i = 0; i < 4; i++) {
#pragma unroll
    for (int r = 0; r < 4; r++) {
      int m = wm0 + i*16 + lr4 + r;
      int bs = bs0 + m;
      const float* T1r = T1 + (size_t)bs*NH + o0;
      size_t orow = ((size_t)bs*NL + l)*NH + o0;
      float awv[NT];
#pragma unroll
      for (int tt = 0; tt < NT; tt++) awv[tt] = aws[m*8 + tt];
#pragma unroll
      for (int j = 0; j < 4; j++) {
        int n = wn0 + j*16 + fr;
        float v = acc[i][j][r] + T1r[n] + b5s[n];
#pragma unroll
        for (int tt = 0; tt < NT; tt++) v += awv[tt] * LBs[tt*128 + n];
        outp[orow + n] = fast_tanh(v);
      }
    }
  }
}

extern "C" void kernel_launch(void* const* d_in, const int* in_sizes, int n_in,
                              void* d_out, int out_size, void* d_ws, size_t ws_size,
                              hipStream_t stream)
{
  const float* token = (const float*)d_in[0];
  const float* label = (const float*)d_in[1];
  const float* imask = (const float*)d_in[2];
  const float* lmask = (const float*)d_in[3];
  const float* W1    = (const float*)d_in[4];
  const float* W2    = (const float*)d_in[5];
  const float* W5    = (const float*)d_in[6];
  const float* b5    = (const float*)d_in[7];
  float* outp = (float*)d_out;

  // ---- workspace layout ----
  char* p = (char*)d_ws;
  float* tkn  = (float*)p; p += (size_t)BS_*NH*4;
  float* T1   = (float*)p; p += (size_t)BS_*NH*4;
  float* lab  = (float*)p; p += (size_t)NLT*NH*4;
  float* LB   = (float*)p; p += (size_t)NLT*NH*4;
  float* aw   = (float*)p; p += (size_t)BS_*NLT*4;
  float* b_in = (float*)p; p += (size_t)BS_*NL*4;
  float* bc   = (float*)p; p += (size_t)BS_*NL*4;
  float* q2c  = (float*)p; p += (size_t)NL*NB*NH*4;

  size_t baseBytes = (size_t)(p - (char*)d_ws);
  const size_t needA = (size_t)NL * BS_ * KTOT * 2;   // 125,829,120 each
  const size_t needW = (size_t)NH * KTOT * 2;         //   2,359,296 each
  bool tier1 = ws_size >= baseBytes + 2*needA + 2*needW;
  u16 *AhG = 0, *AlG = 0, *WhG = 0, *WlG = 0;
  if (tier1) {
    AhG = (u16*)p; p += needA;
    AlG = (u16*)p; p += needA;
    WhG = (u16*)p; p += needW;
    WlG = (u16*)p; p += needW;
  }
  // tier2: bf16 planes for the two pre-GEMMs
  const size_t szTok = (size_t)BS_*NH*2;   // 3,145,728
  const size_t szW   = (size_t)NH*NH*2;    // 1,179,648
  size_t extra2 = 2*szTok*2 + 2*szW*2;
  bool tier2 = tier1 && (ws_size >= (size_t)(p - (char*)d_ws) + extra2);
  u16 *tokh=0,*tokl=0,*w1h=0,*w1l=0,*wb1h=0,*wb1l=0,*tknh=0,*tknl=0;
  if (tier2) {
    tokh = (u16*)p; p += szTok;  tokl = (u16*)p; p += szTok;
    w1h  = (u16*)p; p += szW;    w1l  = (u16*)p; p += szW;
    wb1h = (u16*)p; p += szW;    wb1l = (u16*)p; p += szW;
    tknh = (u16*)p; p += szTok;  tknl = (u16*)p; p += szTok;
  }
  // tier3: lab/scores/LB on MFMA (padded planes)
  const size_t szWb2   = (size_t)NH*NH*2;        // 1,179,648
  const size_t szW2P   = (size_t)NH*NEP*2;       //   491,520
  const size_t szLabel = (size_t)NLTP*NEP*2;     //   163,840
  const size_t szLabP  = (size_t)NLTP*NH*2;      //   393,216
  const size_t szSc    = (size_t)BS_*NLT*4;      // 1,310,720
  size_t extra3 = 2*szWb2 + 2*szW2P + 2*szLabel + 2*szLabP + szSc;
  bool tier3 = tier2 && (ws_size >= (size_t)(p - (char*)d_ws) + extra3);
  u16 *wb2h=0,*wb2l=0,*w2h=0,*w2l=0,*labeh=0,*label_=0,*labh=0,*labl=0;
  float* sc = 0;
  if (tier3) {
    wb2h = (u16*)p; p += szWb2;   wb2l = (u16*)p; p += szWb2;
    w2h  = (u16*)p; p += szW2P;   w2l  = (u16*)p; p += szW2P;
    labeh= (u16*)p; p += szLabel; label_=(u16*)p; p += szLabel;
    labh = (u16*)p; p += szLabP;  labl = (u16*)p; p += szLabP;
    sc   = (float*)p; p += szSc;
  }

  if (tier3) {
    // one launch: all input/weight splits (7 jobs, fully parallel)
    prep_weights<<<dim3(BS_, 7), 256, 0, stream>>>(
        W5, W1, W2, token, label,
        WhG, WlG, w1h, w1l, wb1h, wb1l, wb2h, wb2l,
        w2h, w2l, tokh, tokl, labeh, label_);
    // tkn = token @ W1^T   (+ fused tknh/tknl planes)
    mfma_gemm_plainT<1><<<dim3(BS_/128, NH/128), 256, 0, stream>>>(
        tokh, tokl, w1h, w1l, NH, tkn, NH, BS_, NH, tknh, tknl, NH);
    // T1 = tkn @ W5b1^T
    mfma_gemm_plainT<0><<<dim3(BS_/128, NH/128), 256, 0, stream>>>(
        tknh, tknl, wb1h, wb1l, NH, T1, NH, BS_, NH, 0, 0, 0);
    // lab = label @ W2^T  (+ fused labh/labl planes; pad rows are zero)
    mfma_gemm_plainT<1><<<dim3(NLTP/128, NH/128), 256, 0, stream>>>(
        labeh, label_, w2h, w2l, NEP, lab, NH, NLT, NH, labh, labl, NH);
    // sc = tkn @ lab^T
    mfma_gemm_plainT<0><<<dim3(BS_/128, NLTP/128), 256, 0, stream>>>(
        tknh, tknl, labh, labl, NH, sc, NLT, BS_, NLT, 0, 0, 0);
    // LB = lab @ W5b2^T
    mfma_gemm_plainT<0><<<dim3(NLTP/128, NH/128), 256, 0, stream>>>(
        labh, labl, wb2h, wb2l, NH, LB, NH, NLT, NH, 0, 0, 0);
    aw_kernel<<<BS_, 256, 0, stream>>>(sc, lmask, imask, aw, b_in);
  } else {
    if (tier1)
      prep_split<<<NH, 256, 0, stream>>>(W5, 3072, 1536, KTOT, WhG, WlG);
    if (tier2) {
      prep_split<<<BS_, 256, 0, stream>>>(token, NH, 0, NH, tokh, tokl);
      prep_split<<<NH,  256, 0, stream>>>(W1,    NH, 0, NH, w1h,  w1l);
      prep_split<<<NH,  256, 0, stream>>>(W5,  3072, 0, NH, wb1h, wb1l);
      mfma_gemm_plainT<0><<<dim3(BS_/128, NH/128), 256, 0, stream>>>(
          tokh, tokl, w1h, w1l, NH, tkn, NH, BS_, NH, 0, 0, 0);
      prep_split<<<BS_, 256, 0, stream>>>(tkn, NH, 0, NH, tknh, tknl);
      mfma_gemm_plainT<0><<<dim3(BS_/128, NH/128), 256, 0, stream>>>(
          tknh, tknl, wb1h, wb1l, NH, T1, NH, BS_, NH, 0, 0, 0);
    } else {
      gemm64<<<dim3(BS_/64, NH/64), 256, 0, stream>>>(token, NH, W1, NH, NH, tkn, NH);
      gemm64<<<dim3(BS_/64, NH/64), 256, 0, stream>>>(tkn, NH, W5, 3072, NH, T1, NH);
    }
    lab_kernel<<<NLT, 256, 0, stream>>>(label, W2, lab);
    LB_kernel<<<NLT, 256, 0, stream>>>(lab, W5, LB);
    scores_kernel<<<BS_, 256, 0, stream>>>(tkn, lab, lmask, imask, aw, b_in);
  }

  softs_kernel<<<NB*NL, 256, 0, stream>>>(b_in, bc);
  q2c_kernel2<<<dim3(NB, NH/128), 256, 0, stream>>>(bc, tkn, q2c);

  if (tier1) {
    aprep<<<NL*16, 256, 0, stream>>>(tkn, lab, aw, q2c, AhG, AlG);
    mfma_gemm<<<NL*16*6, 256, 0, stream>>>(AhG, AlG, WhG, WlG, T1, LB, aw, b5, outp);
  } else {
    fused_out<<<dim3(NB*NL*4, NH/64), 256, 0, stream>>>(tkn, lab, aw, q2c, T1, LB, W5, b5, outp);
  }
}

// Round 7
// 642.462 us; speedup vs baseline: 1.2884x; 1.0492x over previous
//
#include <hip/hip_runtime.h>
#include <math.h>
#include <stdint.h>

#define NB 8
#define NS 256
#define NH 768
#define NL 20
#define NT 8
#define NE 300
#define NEGV (-10000.0f)
#define BS_ (NB*NS)          // 2048
#define NLT (NL*NT)          // 160
#define KTOT 1536            // [A1 | A2] concat K for the fused MFMA GEMM
#define NEP 320              // NE padded to mult of 32
#define NLTP 256             // NLT padded to mult of 128

typedef unsigned short u16;
typedef unsigned int   u32;
using short8v = __attribute__((ext_vector_type(8))) short;   // 8 bf16 = 4 VGPR
using f32x4   = __attribute__((ext_vector_type(4))) float;   // MFMA acc

__device__ __forceinline__ float fast_tanh(float x) {
  float e = __expf(2.0f * x);
  return 1.0f - 2.0f / (e + 1.0f);
}
// f32 -> bf16 round-to-nearest-even (bits)
__device__ __forceinline__ u16 f2bh(float f) {
  u32 u = __float_as_uint(f);
  return (u16)((u + 0x7fffu + ((u >> 16) & 1u)) >> 16);
}
__device__ __forceinline__ float bh2f(u16 h) {
  return __uint_as_float(((u32)h) << 16);
}
// async global->LDS, 16B per lane; lds ptr must be wave-uniform base
__device__ __forceinline__ void g2lds16(const void* g, void* s) {
  __builtin_amdgcn_global_load_lds((const __attribute__((address_space(1))) void*)g,
                                   (__attribute__((address_space(3))) void*)s, 16, 0, 0);
}
// Swizzle convention (ALL plane writers/readers): planes are row-major rows of
// K bf16.  Within each 64B k-block (32 values), the 16B chunk holding logical
// chunk c (c=0..3) is stored at position c ^ ((row>>1)&3).
__device__ __forceinline__ int swz_cb(int k0, int row) {
  return ((k0 >> 3) & 3) ^ ((row >> 1) & 3);
}

// ---------------------------------------------------------------------------
// f32 GEMM fallback (tier <2): C[m,n] = sum_k A[m,k]*B[n,k]
// ---------------------------------------------------------------------------
__global__ __launch_bounds__(256)
void gemm64(const float* __restrict__ A, int lda,
            const float* __restrict__ B, int ldb, int K,
            float* __restrict__ C, int ldc)
{
  __shared__ float As[16][64];
  __shared__ float Bs[16][64];
  const int t  = threadIdx.x;
  const int bm = blockIdx.x * 64, bn = blockIdx.y * 64;
  const int tm = t & 15, tn = t >> 4;
  const int lr = t >> 2;
  const int lk = (t & 3) * 4;
  float acc[4][4];
#pragma unroll
  for (int r = 0; r < 4; r++)
#pragma unroll
    for (int c = 0; c < 4; c++) acc[r][c] = 0.f;

  for (int kt = 0; kt < K; kt += 16) {
    float4 a4 = *(const float4*)(A + (size_t)(bm + lr) * lda + kt + lk);
    float4 b4 = *(const float4*)(B + (size_t)(bn + lr) * ldb + kt + lk);
    As[lk+0][lr] = a4.x; As[lk+1][lr] = a4.y; As[lk+2][lr] = a4.z; As[lk+3][lr] = a4.w;
    Bs[lk+0][lr] = b4.x; Bs[lk+1][lr] = b4.y; Bs[lk+2][lr] = b4.z; Bs[lk+3][lr] = b4.w;
    __syncthreads();
#pragma unroll
    for (int k = 0; k < 16; k++) {
      float av[4], bv[4];
#pragma unroll
      for (int r = 0; r < 4; r++) av[r] = As[k][tm*4 + r];
#pragma unroll
      for (int c = 0; c < 4; c++) bv[c] = Bs[k][tn*4 + c];
#pragma unroll
      for (int r = 0; r < 4; r++)
#pragma unroll
        for (int c = 0; c < 4; c++) acc[r][c] += av[r] * bv[c];
    }
    __syncthreads();
  }
#pragma unroll
  for (int r = 0; r < 4; r++)
#pragma unroll
    for (int c = 0; c < 4; c++)
      C[(size_t)(bm + tm*4 + r) * ldc + bn + tn*4 + c] = acc[r][c];
}

// ---- fallback small kernels (tier <3) ----
__global__ __launch_bounds__(256)
void lab_kernel(const float* __restrict__ label, const float* __restrict__ W2,
                float* __restrict__ lab)
{
  int lt = blockIdx.x;
  __shared__ __align__(16) float le[NE];
  for (int e = threadIdx.x; e < NE; e += 256) le[e] = label[(size_t)lt*NE + e];
  __syncthreads();
  for (int o = threadIdx.x; o < NH; o += 256) {
    const float4* wr = (const float4*)(W2 + (size_t)o*NE);
    const float4* l4 = (const float4*)le;
    float s = 0.f;
    for (int e = 0; e < NE/4; e++) {
      float4 a = l4[e], b = wr[e];
      s += a.x*b.x + a.y*b.y + a.z*b.z + a.w*b.w;
    }
    lab[(size_t)lt*NH + o] = s;
  }
}

__global__ __launch_bounds__(256)
void LB_kernel(const float* __restrict__ lab, const float* __restrict__ W5,
               float* __restrict__ LB)
{
  int lt = blockIdx.x;
  __shared__ __align__(16) float lr[NH];
  for (int h = threadIdx.x; h < NH; h += 256) lr[h] = lab[(size_t)lt*NH + h];
  __syncthreads();
  for (int o = threadIdx.x; o < NH; o += 256) {
    const float4* wr = (const float4*)(W5 + (size_t)o*3072 + NH);
    const float4* l4 = (const float4*)lr;
    float s = 0.f;
    for (int h = 0; h < NH/4; h++) {
      float4 a = l4[h], b = wr[h];
      s += a.x*b.x + a.y*b.y + a.z*b.z + a.w*b.w;
    }
    LB[(size_t)lt*NH + o] = s;
  }
}

__global__ __launch_bounds__(256)
void scores_kernel(const float* __restrict__ tkn, const float* __restrict__ lab,
                   const float* __restrict__ lmask, const float* __restrict__ imask,
                   float* __restrict__ aw, float* __restrict__ b_in)
{
  int bs = blockIdx.x;
  __shared__ __align__(16) float trow[NH];
  __shared__ float sc[NLT];
  __shared__ float mL[NL], iL[NL];
  for (int h = threadIdx.x; h < NH; h += 256) trow[h] = tkn[(size_t)bs*NH + h];
  __syncthreads();
  int j = threadIdx.x;
  if (j < NLT) {
    const float4* lrow = (const float4*)(lab + (size_t)j*NH);
    const float4* t4   = (const float4*)trow;
    float s = 0.f;
    for (int h = 0; h < NH/4; h++) {
      float4 a = t4[h], b = lrow[h];
      s += a.x*b.x + a.y*b.y + a.z*b.z + a.w*b.w;
    }
    s += (1.0f - lmask[j]) * NEGV;
    sc[j] = s;
  }
  __syncthreads();
  if (j < NL) {
    float m = sc[j*8];
    for (int t = 1; t < 8; t++) m = fmaxf(m, sc[j*8 + t]);
    float ssum = 0.f;
    for (int t = 0; t < 8; t++) ssum += __expf(sc[j*8 + t] - m);
    mL[j] = m; iL[j] = 1.0f / ssum;
    b_in[(size_t)bs*NL + j] = m + (1.0f - imask[bs]) * NEGV;
  }
  __syncthreads();
  if (j < NLT) aw[(size_t)bs*NLT + j] = __expf(sc[j] - mL[j >> 3]) * iL[j >> 3];
}

// tier3: softmax/aw from precomputed sc[BS_, NLT]
__global__ __launch_bounds__(256)
void aw_kernel(const float* __restrict__ sc_in, const float* __restrict__ lmask,
               const float* __restrict__ imask, float* __restrict__ aw,
               float* __restrict__ b_in)
{
  int bs = blockIdx.x;
  __shared__ float sc[NLT];
  __shared__ float mL[NL], iL[NL];
  int j = threadIdx.x;
  if (j < NLT) sc[j] = sc_in[(size_t)bs*NLT + j] + (1.0f - lmask[j]) * NEGV;
  __syncthreads();
  if (j < NL) {
    float m = sc[j*8];
    for (int t = 1; t < 8; t++) m = fmaxf(m, sc[j*8 + t]);
    float ssum = 0.f;
    for (int t = 0; t < 8; t++) ssum += __expf(sc[j*8 + t] - m);
    mL[j] = m; iL[j] = 1.0f / ssum;
    b_in[(size_t)bs*NL + j] = m + (1.0f - imask[bs]) * NEGV;
  }
  __syncthreads();
  if (j < NLT) aw[(size_t)bs*NLT + j] = __expf(sc[j] - mL[j >> 3]) * iL[j >> 3];
}

__global__ __launch_bounds__(256)
void softs_kernel(const float* __restrict__ b_in, float* __restrict__ bc)
{
  int b = blockIdx.x / NL, l = blockIdx.x % NL;
  int s = threadIdx.x;
  __shared__ float red[256];
  float v = b_in[((size_t)b*NS + s)*NL + l];
  red[s] = v; __syncthreads();
  for (int off = 128; off > 0; off >>= 1) {
    if (s < off) red[s] = fmaxf(red[s], red[s + off]);
    __syncthreads();
  }
  float m = red[0]; __syncthreads();
  float e = __expf(v - m);
  red[s] = e; __syncthreads();
  for (int off = 128; off > 0; off >>= 1) {
    if (s < off) red[s] += red[s + off];
    __syncthreads();
  }
  bc[((size_t)b*NS + s)*NL + l] = e / red[0];
}

// q2c[b,l,h] = sum_s bc[b,s,l]*tkn[b,s,h].  Grid (NB, NH/128).
__global__ __launch_bounds__(256)
void q2c_kernel2(const float* __restrict__ bc, const float* __restrict__ tkn,
                 float* __restrict__ q2c)
{
  const int b  = blockIdx.x;
  const int h0 = blockIdx.y * 128;
  const int t  = threadIdx.x;
  const int th = t & 127, half = t >> 7;
  __shared__ __align__(16) float bcS[NS*NL];        // 20 KB
  __shared__ __align__(16) float4 part[2*5*128];    // 20 KB
  for (int i = t; i < NS*NL; i += 256) bcS[i] = bc[(size_t)b*NS*NL + i];
  __syncthreads();
  float4 acc[5];
#pragma unroll
  for (int g = 0; g < 5; g++) acc[g] = {0.f, 0.f, 0.f, 0.f};
  const int h = h0 + th;
  for (int s = half*128; s < half*128 + 128; s++) {
    float tv = tkn[((size_t)b*NS + s)*NH + h];
    const float4* bl4 = (const float4*)(bcS + s*NL);
#pragma unroll
    for (int g = 0; g < 5; g++) {
      float4 w = bl4[g];
      acc[g].x += w.x*tv; acc[g].y += w.y*tv; acc[g].z += w.z*tv; acc[g].w += w.w*tv;
    }
  }
#pragma unroll
  for (int g = 0; g < 5; g++) part[(half*5 + g)*128 + th] = acc[g];
  __syncthreads();
  if (half == 0) {
#pragma unroll
    for (int g = 0; g < 5; g++) {
      float4 a = part[g*128 + th], c = part[(5 + g)*128 + th];
#pragma unroll
      for (int cc = 0; cc < 4; cc++) {
        int l = g*4 + cc;
        float v = ((const float*)&a)[cc] + ((const float*)&c)[cc];
        q2c[((size_t)(b*NL + l))*NH + h] = v;
      }
    }
  }
}

// ---------------------------------------------------------------------------
// OLD fused_out — fallback when ws can't even hold the fused-GEMM planes.
// ---------------------------------------------------------------------------
__global__ __launch_bounds__(256)
void fused_out(const float* __restrict__ tkn, const float* __restrict__ lab,
               const float* __restrict__ aw, const float* __restrict__ q2c,
               const float* __restrict__ T1, const float* __restrict__ LB,
               const float* __restrict__ W5, const float* __restrict__ b5,
               float* __restrict__ outp)
{
  const int t  = threadIdx.x;
  const int sq = blockIdx.x & 3;
  const int l  = (blockIdx.x >> 2) % NL;
  const int b  = blockIdx.x / (4 * NL);
  const int o0 = blockIdx.y * 64;
  const int s0 = sq * 64;
  const int tm = t & 15, tn = t >> 4;
  const int lr = t >> 2;
  const int lk = (t & 3) * 4;

  __shared__ float A1s[16][64];
  __shared__ float A2s[16][64];
  __shared__ float Cs[16][64];
  __shared__ float Ds[16][64];
  __shared__ float labS[NT][16];
  __shared__ float q2cS[16];
  __shared__ float awS[64][NT];
  __shared__ float LBS[NT][64];
  __shared__ float b5S[64];

  for (int i = t; i < 64*NT; i += 256) {
    int m = i >> 3, tt = i & 7;
    awS[m][tt] = aw[(size_t)(b*NS + s0 + m) * NLT + l*NT + tt];
  }
  for (int i = t; i < NT*64; i += 256) {
    int tt = i >> 6, n = i & 63;
    LBS[tt][n] = LB[(size_t)(l*NT + tt) * NH + o0 + n];
  }
  if (t < 64) b5S[t] = b5[o0 + t];

  float acc[4][4];
#pragma unroll
  for (int r = 0; r < 4; r++)
#pragma unroll
    for (int c = 0; c < 4; c++) acc[r][c] = 0.f;

  for (int kt = 0; kt < NH; kt += 16) {
    if (t < 128) { int tt = t >> 4, k = t & 15; labS[tt][k] = lab[(size_t)(l*NT + tt)*NH + kt + k]; }
    if (t < 16)  q2cS[t] = q2c[(size_t)(b*NL + l)*NH + kt + t];
    {
      float4 c4 = *(const float4*)(W5 + (size_t)(o0 + lr)*3072 + 1536 + kt + lk);
      Cs[lk+0][lr] = c4.x; Cs[lk+1][lr] = c4.y; Cs[lk+2][lr] = c4.z; Cs[lk+3][lr] = c4.w;
      float4 d4 = *(const float4*)(W5 + (size_t)(o0 + lr)*3072 + 2304 + kt + lk);
      Ds[lk+0][lr] = d4.x; Ds[lk+1][lr] = d4.y; Ds[lk+2][lr] = d4.z; Ds[lk+3][lr] = d4.w;
    }
    __syncthreads();
    {
      float4 t4 = *(const float4*)(tkn + (size_t)(b*NS + s0 + lr)*NH + kt + lk);
      float tv[4] = {t4.x, t4.y, t4.z, t4.w};
#pragma unroll
      for (int j = 0; j < 4; j++) {
        int k = lk + j;
        float c2 = 0.f;
#pragma unroll
        for (int tt = 0; tt < NT; tt++) c2 += awS[lr][tt] * labS[tt][k];
        A1s[k][lr] = tv[j] * c2;
        A2s[k][lr] = tv[j] * q2cS[k];
      }
    }
    __syncthreads();
#pragma unroll
    for (int k = 0; k < 16; k++) {
      float a1[4], a2[4], wc[4], wd[4];
#pragma unroll
      for (int r = 0; r < 4; r++) { a1[r] = A1s[k][tm*4 + r]; a2[r] = A2s[k][tm*4 + r]; }
#pragma unroll
      for (int c = 0; c < 4; c++) { wc[c] = Cs[k][tn*4 + c]; wd[c] = Ds[k][tn*4 + c]; }
#pragma unroll
      for (int r = 0; r < 4; r++)
#pragma unroll
        for (int c = 0; c < 4; c++)
          acc[r][c] += a1[r]*wc[c] + a2[r]*wd[c];
    }
    __syncthreads();
  }

#pragma unroll
  for (int r = 0; r < 4; r++) {
    int m = tm*4 + r;
    int s = s0 + m;
    size_t orow = ((size_t)(b*NS + s)*NL + l)*NH + o0;
    const float* T1r = T1 + (size_t)(b*NS + s)*NH + o0;
#pragma unroll
    for (int c = 0; c < 4; c++) {
      int n = tn*4 + c;
      float v = acc[r][c] + T1r[n] + b5S[n];
#pragma unroll
      for (int tt = 0; tt < NT; tt++) v += awS[m][tt] * LBS[tt][n];
      outp[orow + n] = fast_tanh(v);
    }
  }
}

// ---------------------------------------------------------------------------
// Generic f32 -> bf16 hi/lo split into the swizzled plane layout (fallback).
// ---------------------------------------------------------------------------
__global__ __launch_bounds__(256)
void prep_split(const float* __restrict__ src, int srcStride, int k0src, int K,
                u16* __restrict__ hi, u16* __restrict__ lo)
{
  const int r = blockIdx.x;
  const float* srow = src + (size_t)r*srcStride + k0src;
  for (int c = threadIdx.x; c < (K >> 3); c += 256) {
    int k0 = c * 8;
    union { u16 a[8]; short8v v; } ph, pl;
#pragma unroll
    for (int j = 0; j < 8; j++) {
      float v = srow[k0 + j];
      u16 h = f2bh(v);
      ph.a[j] = h;
      pl.a[j] = f2bh(v - bh2f(h));
    }
    size_t base = (size_t)r*K + (size_t)(k0 >> 5)*32 + swz_cb(k0, r)*8;
    *(short8v*)(hi + base) = ph.v;
    *(short8v*)(lo + base) = pl.v;
  }
}

__global__ __launch_bounds__(256)
void prep_split_pad(const float* __restrict__ src, int srcStride, int Ksrc, int Rsrc,
                    int K, u16* __restrict__ hi, u16* __restrict__ lo)
{
  const int r = blockIdx.x;
  const bool rok = r < Rsrc;
  const float* srow = src + (size_t)r*srcStride;
  for (int c = threadIdx.x; c < (K >> 3); c += 256) {
    int k0 = c * 8;
    union { u16 a[8]; short8v v; } ph, pl;
#pragma unroll
    for (int j = 0; j < 8; j++) {
      float v = (rok && (k0 + j) < Ksrc) ? srow[k0 + j] : 0.f;
      u16 h = f2bh(v);
      ph.a[j] = h;
      pl.a[j] = f2bh(v - bh2f(h));
    }
    size_t base = (size_t)r*K + (size_t)(k0 >> 5)*32 + swz_cb(k0, r)*8;
    *(short8v*)(hi + base) = ph.v;
    *(short8v*)(lo + base) = pl.v;
  }
}

// tier3: ALL independent input/weight splits in ONE launch.  grid (2048, 7).
__global__ __launch_bounds__(256)
void prep_weights(const float* __restrict__ W5, const float* __restrict__ W1,
                  const float* __restrict__ W2, const float* __restrict__ token,
                  const float* __restrict__ label,
                  u16* __restrict__ Wh,   u16* __restrict__ Wl,
                  u16* __restrict__ w1h,  u16* __restrict__ w1l,
                  u16* __restrict__ wb1h, u16* __restrict__ wb1l,
                  u16* __restrict__ wb2h, u16* __restrict__ wb2l,
                  u16* __restrict__ w2h,  u16* __restrict__ w2l,
                  u16* __restrict__ tokh, u16* __restrict__ tokl,
                  u16* __restrict__ labeh, u16* __restrict__ label_)
{
  const int job = blockIdx.y;
  const int r = blockIdx.x;
  const float* src; int stride, Ksrc, K, Rsrc, Rplane; u16 *hi, *lo;
  switch (job) {
    case 0: src = W5 + 1536; stride = 3072; Ksrc = 1536; K = KTOT; Rsrc = NH;  Rplane = NH;   hi = Wh;   lo = Wl;   break;
    case 1: src = W1;        stride = NH;   Ksrc = NH;   K = NH;   Rsrc = NH;  Rplane = NH;   hi = w1h;  lo = w1l;  break;
    case 2: src = W5;        stride = 3072; Ksrc = NH;   K = NH;   Rsrc = NH;  Rplane = NH;   hi = wb1h; lo = wb1l; break;
    case 3: src = W5 + NH;   stride = 3072; Ksrc = NH;   K = NH;   Rsrc = NH;  Rplane = NH;   hi = wb2h; lo = wb2l; break;
    case 4: src = W2;        stride = NE;   Ksrc = NE;   K = NEP;  Rsrc = NH;  Rplane = NH;   hi = w2h;  lo = w2l;  break;
    case 5: src = token;     stride = NH;   Ksrc = NH;   K = NH;   Rsrc = BS_; Rplane = BS_;  hi = tokh; lo = tokl; break;
    default: src = label;    stride = NE;   Ksrc = NE;   K = NEP;  Rsrc = NLT; Rplane = NLTP; hi = labeh; lo = label_; break;
  }
  if (r >= Rplane) return;
  const bool rok = r < Rsrc;
  const float* srow = src + (size_t)r*stride;
  for (int c = threadIdx.x; c < (K >> 3); c += 256) {
    int k0 = c * 8;
    union { u16 a[8]; short8v v; } ph, pl;
#pragma unroll
    for (int j = 0; j < 8; j++) {
      float v = (rok && (k0 + j) < Ksrc) ? srow[k0 + j] : 0.f;
      u16 h = f2bh(v);
      ph.a[j] = h;
      pl.a[j] = f2bh(v - bh2f(h));
    }
    size_t base = (size_t)r*K + (size_t)(k0 >> 5)*32 + swz_cb(k0, r)*8;
    *(short8v*)(hi + base) = ph.v;
    *(short8v*)(lo + base) = pl.v;
  }
}

// A' rows ordered [l][bs]:  A'[row][0:768) = tkn.*c2q,  [768:1536) = tkn.*q2c.
// Wave-tile [4 rows x 16 chunks]: 16 consecutive lanes cover a 256B contiguous
// run of ONE plane row (coalesced).  (Round-6 fix, verified −154 µs.)
__global__ __launch_bounds__(256)
void aprep(const float* __restrict__ tkn, const float* __restrict__ lab,
           const float* __restrict__ aw, const float* __restrict__ q2c,
           u16* __restrict__ Ah, u16* __restrict__ Al)
{
  const int l   = blockIdx.x >> 4;
  const int bs0 = (blockIdx.x & 15) << 7;     // 128-row chunk, same b throughout
  const int b   = bs0 >> 8;
  const int t   = threadIdx.x;
  __shared__ float labS[NT][NH];
  __shared__ float q2cS[NH];
  __shared__ float awT[NT][128];
  for (int i = t; i < NT*NH; i += 256) { int tt = i / NH, k = i % NH; labS[tt][k] = lab[(size_t)(l*NT+tt)*NH + k]; }
  for (int i = t; i < NH; i += 256) q2cS[i] = q2c[(size_t)(b*NL + l)*NH + i];
  for (int i = t; i < NT*128; i += 256) { int tt = i >> 7, m = i & 127; awT[tt][m] = aw[(size_t)(bs0+m)*NLT + l*NT + tt]; }
  __syncthreads();

  const int w    = t >> 6;        // wave 0..3
  const int l6   = t & 63;
  const int mloc = l6 >> 4;       // 0..3   (row within wave tile)
  const int c16  = l6 & 15;       // 0..15  (chunk within wave tile)

  for (int ii = 0; ii < 48; ii++) {
    const int ct = ii % 6, rt = ii / 6;
    const int m  = rt*16 + w*4 + mloc;
    const int c  = ct*16 + c16;
    const int k0 = c * 8;
    const int bs = bs0 + m;
    const float* trow = tkn + (size_t)bs*NH + k0;
    float4 t4a = *(const float4*)(trow);
    float4 t4b = *(const float4*)(trow + 4);
    float tv[8] = {t4a.x, t4a.y, t4a.z, t4a.w, t4b.x, t4b.y, t4b.z, t4b.w};
    float awv[NT];
#pragma unroll
    for (int tt = 0; tt < NT; tt++) awv[tt] = awT[tt][m];

    union { u16 a[8]; short8v v; } h1, l1, h2, l2;
#pragma unroll
    for (int j = 0; j < 8; j++) {
      float cq = 0.f;
#pragma unroll
      for (int tt = 0; tt < NT; tt++) cq += awv[tt] * labS[tt][k0+j];
      float x1 = tv[j] * cq;
      float x2 = tv[j] * q2cS[k0+j];
      u16 h = f2bh(x1); h1.a[j] = h; l1.a[j] = f2bh(x1 - bh2f(h));
      u16 g = f2bh(x2); h2.a[j] = g; l2.a[j] = f2bh(x2 - bh2f(g));
    }
    size_t rowbase = ((size_t)l*BS_ + bs) * KTOT;
    size_t d1 = rowbase + (size_t)(k0 >> 5)*32 + swz_cb(k0, m)*8;
    size_t d2 = d1 + NH;
    *(short8v*)(Ah + d1) = h1.v;
    *(short8v*)(Al + d1) = l1.v;
    *(short8v*)(Ah + d2) = h2.v;
    *(short8v*)(Al + d2) = l2.v;
  }
}

// ---------------------------------------------------------------------------
// Plain 3-term MFMA GEMM, double-buffered (BK=32, 2x32KB LDS, counted vmcnt).
// (verified; unchanged — small dispatches only)
// ---------------------------------------------------------------------------
template<int OUT>
__global__ __launch_bounds__(256)
void mfma_gemm_plainT(const u16* __restrict__ AhG, const u16* __restrict__ AlG,
                      const u16* __restrict__ BhG, const u16* __restrict__ BlG,
                      int K, float* __restrict__ C, int ldc, int Mv, int Nv,
                      u16* __restrict__ Ph, u16* __restrict__ Pl, int Kp)
{
  __shared__ __align__(16) char lds[65536];

  const int m0 = blockIdx.x * 128, n0 = blockIdx.y * 128;
  const int t = threadIdx.x;
  const int wv = t >> 6, lane = t & 63;
  const int wm0 = (wv >> 1) << 6;
  const int wn0 = (wv & 1) << 6;
  const int fr = lane & 15;
  const int g  = lane >> 4;
  const int r0 = wv*32 + (lane >> 2);
  const int cpos = (lane & 3) * 16;

  const size_t rowb = (size_t)K * 2;
  const char* gAh = (const char*)AhG + (size_t)m0 * rowb;
  const char* gAl = (const char*)AlG + (size_t)m0 * rowb;
  const char* gBh = (const char*)BhG + (size_t)n0 * rowb;
  const char* gBl = (const char*)BlG + (size_t)n0 * rowb;
  const size_t gs = 16 * rowb;

  f32x4 acc[4][4];
  f32x4 zz = {0.f, 0.f, 0.f, 0.f};
#pragma unroll
  for (int i = 0; i < 4; i++)
#pragma unroll
    for (int j = 0; j < 4; j++) acc[i][j] = zz;

  auto stage = [&](int kb, int half) {
    size_t ga = (size_t)r0 * rowb + (size_t)kb * 64 + cpos;
    char* base = lds + half*32768 + wv*2048;
    g2lds16(gAh + ga, base);           g2lds16(gAh + ga + gs, base + 1024);
    g2lds16(gAl + ga, base + 8192);    g2lds16(gAl + ga + gs, base + 9216);
    g2lds16(gBh + ga, base + 16384);   g2lds16(gBh + ga + gs, base + 17408);
    g2lds16(gBl + ga, base + 24576);   g2lds16(gBl + ga + gs, base + 25600);
  };

  const int nkb = K >> 5;
  stage(0, 0);
  for (int kb = 0; kb < nkb; kb++) {
    const int cur = kb & 1;
    if (kb + 1 < nkb) {
      stage(kb + 1, cur ^ 1);
      asm volatile("s_waitcnt vmcnt(8)" ::: "memory");
    } else {
      asm volatile("s_waitcnt vmcnt(0)" ::: "memory");
    }
    __builtin_amdgcn_s_barrier();
    __builtin_amdgcn_sched_barrier(0);

    const char* ldsAh = lds + cur*32768;
    const char* ldsAl = ldsAh + 8192;
    const char* ldsBh = ldsAh + 16384;
    const char* ldsBl = ldsAh + 24576;
    const int xk = ((g ^ ((fr >> 1) & 3)) << 4);
    short8v bh[4], bl[4];
#pragma unroll
    for (int j = 0; j < 4; j++) {
      int n = wn0 + j*16 + fr;
      bh[j] = *(const short8v*)(ldsBh + n*64 + xk);
      bl[j] = *(const short8v*)(ldsBl + n*64 + xk);
    }
    __builtin_amdgcn_s_setprio(1);
#pragma unroll
    for (int i = 0; i < 4; i++) {
      int m = wm0 + i*16 + fr;
      short8v ah = *(const short8v*)(ldsAh + m*64 + xk);
      short8v al = *(const short8v*)(ldsAl + m*64 + xk);
#pragma unroll
      for (int j = 0; j < 4; j++) {
        acc[i][j] = __builtin_amdgcn_mfma_f32_16x16x32_bf16(ah, bh[j], acc[i][j], 0, 0, 0);
        acc[i][j] = __builtin_amdgcn_mfma_f32_16x16x32_bf16(ah, bl[j], acc[i][j], 0, 0, 0);
        acc[i][j] = __builtin_amdgcn_mfma_f32_16x16x32_bf16(al, bh[j], acc[i][j], 0, 0, 0);
      }
    }
    __builtin_amdgcn_s_setprio(0);
    __builtin_amdgcn_sched_barrier(0);
    __builtin_amdgcn_s_barrier();
  }

  const int lr4 = (lane >> 4) * 4;
#pragma unroll
  for (int i = 0; i < 4; i++) {
#pragma unroll
    for (int r = 0; r < 4; r++) {
      int m = m0 + wm0 + i*16 + lr4 + r;
      float* Cr = C + (size_t)m * ldc + n0;
#pragma unroll
      for (int j = 0; j < 4; j++) {
        int nl = wn0 + j*16 + fr;
        int n = n0 + nl;
        float v = acc[i][j][r];
        if (m < Mv && n < Nv) Cr[nl] = v;
        if constexpr (OUT == 1) {
          u16 h = f2bh(v);
          u16 lo2 = f2bh(v - bh2f(h));
          size_t po = (size_t)m*Kp + (size_t)((n >> 5) << 5)
                    + ((((n >> 3) & 3) ^ ((m >> 1) & 3)) << 3) + (n & 7);
          Ph[po] = h;
          Pl[po] = lo2;
        }
      }
    }
  }
}

// ---------------------------------------------------------------------------
// Fused MFMA GEMM + epilogue — ROUND-7: 512 threads / 8 waves per block at the
// SAME 128x128 tile and identical dbuf+counted-vmcnt skeleton.  acc per wave
// halves (64x32 output) -> ~90 VGPR -> 4 waves/SIMD (two independent blocks
// interleave: m114 TLP mechanism hides the vmcnt/barrier drains).
// ---------------------------------------------------------------------------
__global__ __launch_bounds__(512, 4)
void mfma_gemm(const u16* __restrict__ AhG, const u16* __restrict__ AlG,
               const u16* __restrict__ WhG, const u16* __restrict__ WlG,
               const float* __restrict__ T1, const float* __restrict__ LBt,
               const float* __restrict__ aw, const float* __restrict__ b5,
               float* __restrict__ outp)
{
  __shared__ __align__(16) char lds[65536];

  int id = blockIdx.x;
  int swz = (id & 7) * 240 + (id >> 3);
  const int nb  = swz % 6;
  const int mbk = swz / 6;
  const int l   = mbk >> 4;
  const int bs0 = (mbk & 15) << 7;
  const int o0  = nb << 7;

  const int t = threadIdx.x;
  const int wv = t >> 6, lane = t & 63;
  const int wm0 = (wv >> 2) << 6;      // 0 / 64      (2 M-groups of waves)
  const int wn0 = (wv & 3) << 5;       // 0/32/64/96  (4 N-groups of waves)
  const int fr = lane & 15;
  const int g  = lane >> 4;

  const char* gAh = (const char*)AhG + ((size_t)l*BS_ + bs0) * (KTOT*2);
  const char* gAl = (const char*)AlG + ((size_t)l*BS_ + bs0) * (KTOT*2);
  const char* gWh = (const char*)WhG + (size_t)o0 * (KTOT*2);
  const char* gWl = (const char*)WlG + (size_t)o0 * (KTOT*2);

  f32x4 acc[4][2];
  f32x4 zz = {0.f, 0.f, 0.f, 0.f};
#pragma unroll
  for (int i = 0; i < 4; i++)
#pragma unroll
    for (int j = 0; j < 2; j++) acc[i][j] = zz;

  // staging: 512 threads x 4 planes x 16B = 32KB/step.  Per wave: 1 instr per
  // plane, 1KB (wave-uniform LDS base wv*1024 + implicit lane*16).  Global:
  // row = t>>2 (0..127), chunk = (t&3)*16 -- matches linear LDS layout.
  auto stage = [&](int kb, int half) {
    size_t ga = (size_t)(t >> 2) * (KTOT*2) + (size_t)kb * 64 + (t & 3) * 16;
    char* base = lds + half*32768 + wv*1024;
    g2lds16(gAh + ga, base);
    g2lds16(gAl + ga, base + 8192);
    g2lds16(gWh + ga, base + 16384);
    g2lds16(gWl + ga, base + 24576);
  };

  const int nkb = KTOT/32;
  stage(0, 0);
  for (int kb = 0; kb < nkb; kb++) {
    const int cur = kb & 1;
    if (kb + 1 < nkb) {
      stage(kb + 1, cur ^ 1);
      asm volatile("s_waitcnt vmcnt(4)" ::: "memory");   // 4 outstanding = next tile
    } else {
      asm volatile("s_waitcnt vmcnt(0)" ::: "memory");
    }
    __builtin_amdgcn_s_barrier();
    __builtin_amdgcn_sched_barrier(0);

    const char* ldsAh = lds + cur*32768;
    const char* ldsAl = ldsAh + 8192;
    const char* ldsWh = ldsAh + 16384;
    const char* ldsWl = ldsAh + 24576;
    const int xk = ((g ^ ((fr >> 1) & 3)) << 4);
    short8v wh[2], wl[2];
#pragma unroll
    for (int j = 0; j < 2; j++) {
      int n = wn0 + j*16 + fr;
      wh[j] = *(const short8v*)(ldsWh + n*64 + xk);
      wl[j] = *(const short8v*)(ldsWl + n*64 + xk);
    }
    __builtin_amdgcn_s_setprio(1);
#pragma unroll
    for (int i = 0; i < 4; i++) {
      int m = wm0 + i*16 + fr;
      short8v ah = *(const short8v*)(ldsAh + m*64 + xk);
      short8v al = *(const short8v*)(ldsAl + m*64 + xk);
#pragma unroll
      for (int j = 0; j < 2; j++) {
        acc[i][j] = __builtin_amdgcn_mfma_f32_16x16x32_bf16(ah, wh[j], acc[i][j], 0, 0, 0);
        acc[i][j] = __builtin_amdgcn_mfma_f32_16x16x32_bf16(ah, wl[j], acc[i][j], 0, 0, 0);
        acc[i][j] = __builtin_amdgcn_mfma_f32_16x16x32_bf16(al, wh[j], acc[i][j], 0, 0, 0);
      }
    }
    __builtin_amdgcn_s_setprio(0);
    __builtin_amdgcn_sched_barrier(0);
    __builtin_amdgcn_s_barrier();
  }

  // epilogue: reuse LDS for LB slice / aw / b5 (single l per block).
  float* LBs = (float*)lds;               // [8][128]
  float* aws = (float*)(lds + 4096);      // [128][8]
  float* b5s = (float*)(lds + 8192);      // [128]
  for (int i = t; i < NT*128; i += 512) { int tt = i >> 7, n = i & 127; LBs[i] = LBt[(size_t)(l*NT+tt)*NH + o0 + n]; }
  for (int i = t; i < 128*NT; i += 512) { int m = i >> 3, tt = i & 7; aws[i] = aw[(size_t)(bs0+m)*NLT + l*NT + tt]; }
  if (t < 128) b5s[t] = b5[o0 + t];
  __syncthreads();

  const int lr4 = (lane >> 4) * 4;        // C/D: row = (lane>>4)*4 + reg, col = lane&15
#pragma unroll
  for (int i = 0; i < 4; i++) {
#pragma unroll
    for (int r = 0; r < 4; r++) {
      int m = wm0 + i*16 + lr4 + r;
      int bs = bs0 + m;
      const float* T1r = T1 + (size_t)bs*NH + o0;
      size_t orow = ((size_t)bs*NL + l)*NH + o0;
      float awv[NT];
#pragma unroll
      for (int tt = 0; tt < NT; tt++) awv[tt] = aws[m*8 + tt];
#pragma unroll
      for (int j = 0; j < 2; j++) {
        int n = wn0 + j*16 + fr;
        float v = acc[i][j][r] + T1r[n] + b5s[n];
#pragma unroll
        for (int tt = 0; tt < NT; tt++) v += awv[tt] * LBs[tt*128 + n];
        outp[orow + n] = fast_tanh(v);
      }
    }
  }
}

extern "C" void kernel_launch(void* const* d_in, const int* in_sizes, int n_in,
                              void* d_out, int out_size, void* d_ws, size_t ws_size,
                              hipStream_t stream)
{
  const float* token = (const float*)d_in[0];
  const float* label = (const float*)d_in[1];
  const float* imask = (const float*)d_in[2];
  const float* lmask = (const float*)d_in[3];
  const float* W1    = (const float*)d_in[4];
  const float* W2    = (const float*)d_in[5];
  const float* W5    = (const float*)d_in[6];
  const float* b5    = (const float*)d_in[7];
  float* outp = (float*)d_out;

  // ---- workspace layout ----
  char* p = (char*)d_ws;
  float* tkn  = (float*)p; p += (size_t)BS_*NH*4;
  float* T1   = (float*)p; p += (size_t)BS_*NH*4;
  float* lab  = (float*)p; p += (size_t)NLT*NH*4;
  float* LB   = (float*)p; p += (size_t)NLT*NH*4;
  float* aw   = (float*)p; p += (size_t)BS_*NLT*4;
  float* b_in = (float*)p; p += (size_t)BS_*NL*4;
  float* bc   = (float*)p; p += (size_t)BS_*NL*4;
  float* q2c  = (float*)p; p += (size_t)NL*NB*NH*4;

  size_t baseBytes = (size_t)(p - (char*)d_ws);
  const size_t needA = (size_t)NL * BS_ * KTOT * 2;   // 125,829,120 each
  const size_t needW = (size_t)NH * KTOT * 2;         //   2,359,296 each
  bool tier1 = ws_size >= baseBytes + 2*needA + 2*needW;
  u16 *AhG = 0, *AlG = 0, *WhG = 0, *WlG = 0;
  if (tier1) {
    AhG = (u16*)p; p += needA;
    AlG = (u16*)p; p += needA;
    WhG = (u16*)p; p += needW;
    WlG = (u16*)p; p += needW;
  }
  // tier2: bf16 planes for the two pre-GEMMs
  const size_t szTok = (size_t)BS_*NH*2;   // 3,145,728
  const size_t szW   = (size_t)NH*NH*2;    // 1,179,648
  size_t extra2 = 2*szTok*2 + 2*szW*2;
  bool tier2 = tier1 && (ws_size >= (size_t)(p - (char*)d_ws) + extra2);
  u16 *tokh=0,*tokl=0,*w1h=0,*w1l=0,*wb1h=0,*wb1l=0,*tknh=0,*tknl=0;
  if (tier2) {
    tokh = (u16*)p; p += szTok;  tokl = (u16*)p; p += szTok;
    w1h  = (u16*)p; p += szW;    w1l  = (u16*)p; p += szW;
    wb1h = (u16*)p; p += szW;    wb1l = (u16*)p; p += szW;
    tknh = (u16*)p; p += szTok;  tknl = (u16*)p; p += szTok;
  }
  // tier3: lab/scores/LB on MFMA (padded planes)
  const size_t szWb2   = (size_t)NH*NH*2;        // 1,179,648
  const size_t szW2P   = (size_t)NH*NEP*2;       //   491,520
  const size_t szLabel = (size_t)NLTP*NEP*2;     //   163,840
  const size_t szLabP  = (size_t)NLTP*NH*2;      //   393,216
  const size_t szSc    = (size_t)BS_*NLT*4;      // 1,310,720
  size_t extra3 = 2*szWb2 + 2*szW2P + 2*szLabel + 2*szLabP + szSc;
  bool tier3 = tier2 && (ws_size >= (size_t)(p - (char*)d_ws) + extra3);
  u16 *wb2h=0,*wb2l=0,*w2h=0,*w2l=0,*labeh=0,*label_=0,*labh=0,*labl=0;
  float* sc = 0;
  if (tier3) {
    wb2h = (u16*)p; p += szWb2;   wb2l = (u16*)p; p += szWb2;
    w2h  = (u16*)p; p += szW2P;   w2l  = (u16*)p; p += szW2P;
    labeh= (u16*)p; p += szLabel; label_=(u16*)p; p += szLabel;
    labh = (u16*)p; p += szLabP;  labl = (u16*)p; p += szLabP;
    sc   = (float*)p; p += szSc;
  }

  if (tier3) {
    prep_weights<<<dim3(BS_, 7), 256, 0, stream>>>(
        W5, W1, W2, token, label,
        WhG, WlG, w1h, w1l, wb1h, wb1l, wb2h, wb2l,
        w2h, w2l, tokh, tokl, labeh, label_);
    mfma_gemm_plainT<1><<<dim3(BS_/128, NH/128), 256, 0, stream>>>(
        tokh, tokl, w1h, w1l, NH, tkn, NH, BS_, NH, tknh, tknl, NH);
    mfma_gemm_plainT<0><<<dim3(BS_/128, NH/128), 256, 0, stream>>>(
        tknh, tknl, wb1h, wb1l, NH, T1, NH, BS_, NH, 0, 0, 0);
    mfma_gemm_plainT<1><<<dim3(NLTP/128, NH/128), 256, 0, stream>>>(
        labeh, label_, w2h, w2l, NEP, lab, NH, NLT, NH, labh, labl, NH);
    mfma_gemm_plainT<0><<<dim3(BS_/128, NLTP/128), 256, 0, stream>>>(
        tknh, tknl, labh, labl, NH, sc, NLT, BS_, NLT, 0, 0, 0);
    mfma_gemm_plainT<0><<<dim3(NLTP/128, NH/128), 256, 0, stream>>>(
        labh, labl, wb2h, wb2l, NH, LB, NH, NLT, NH, 0, 0, 0);
    aw_kernel<<<BS_, 256, 0, stream>>>(sc, lmask, imask, aw, b_in);
  } else {
    if (tier1)
      prep_split<<<NH, 256, 0, stream>>>(W5, 3072, 1536, KTOT, WhG, WlG);
    if (tier2) {
      prep_split<<<BS_, 256, 0, stream>>>(token, NH, 0, NH, tokh, tokl);
      prep_split<<<NH,  256, 0, stream>>>(W1,    NH, 0, NH, w1h,  w1l);
      prep_split<<<NH,  256, 0, stream>>>(W5,  3072, 0, NH, wb1h, wb1l);
      mfma_gemm_plainT<0><<<dim3(BS_/128, NH/128), 256, 0, stream>>>(
          tokh, tokl, w1h, w1l, NH, tkn, NH, BS_, NH, 0, 0, 0);
      prep_split<<<BS_, 256, 0, stream>>>(tkn, NH, 0, NH, tknh, tknl);
      mfma_gemm_plainT<0><<<dim3(BS_/128, NH/128), 256, 0, stream>>>(
          tknh, tknl, wb1h, wb1l, NH, T1, NH, BS_, NH, 0, 0, 0);
    } else {
      gemm64<<<dim3(BS_/64, NH/64), 256, 0, stream>>>(token, NH, W1, NH, NH, tkn, NH);
      gemm64<<<dim3(BS_/64, NH/64), 256, 0, stream>>>(tkn, NH, W5, 3072, NH, T1, NH);
    }
    lab_kernel<<<NLT, 256, 0, stream>>>(label, W2, lab);
    LB_kernel<<<NLT, 256, 0, stream>>>(lab, W5, LB);
    scores_kernel<<<BS_, 256, 0, stream>>>(tkn, lab, lmask, imask, aw, b_in);
  }

  softs_kernel<<<NB*NL, 256, 0, stream>>>(b_in, bc);
  q2c_kernel2<<<dim3(NB, NH/128), 256, 0, stream>>>(bc, tkn, q2c);

  if (tier1) {
    aprep<<<NL*16, 256, 0, stream>>>(tkn, lab, aw, q2c, AhG, AlG);
    mfma_gemm<<<NL*16*6, 512, 0, stream>>>(AhG, AlG, WhG, WlG, T1, LB, aw, b5, outp);
  } else {
    fused_out<<<dim3(NB*NL*4, NH/64), 256, 0, stream>>>(tkn, lab, aw, q2c, T1, LB, W5, b5, outp);
  }
}

// Round 8
// 534.276 us; speedup vs baseline: 1.5493x; 1.2025x over previous
//
#include <hip/hip_runtime.h>
#include <math.h>
#include <stdint.h>

#define NB 8
#define NS 256
#define NH 768
#define NL 20
#define NT 8
#define NE 300
#define NEGV (-10000.0f)
#define BS_ (NB*NS)          // 2048
#define NLT (NL*NT)          // 160
#define KTOT 1536            // [A1 | A2] concat K for the fused MFMA GEMM
#define NEP 320              // NE padded to mult of 32
#define NLTP 256             // NLT padded to mult of 128

typedef unsigned short u16;
typedef unsigned int   u32;
using short8v = __attribute__((ext_vector_type(8))) short;   // 8 bf16 = 4 VGPR
using f32x4   = __attribute__((ext_vector_type(4))) float;   // MFMA acc

__device__ __forceinline__ float fast_tanh(float x) {
  float e = __expf(2.0f * x);
  return 1.0f - 2.0f / (e + 1.0f);
}
// f32 -> bf16 round-to-nearest-even (bits)
__device__ __forceinline__ u16 f2bh(float f) {
  u32 u = __float_as_uint(f);
  return (u16)((u + 0x7fffu + ((u >> 16) & 1u)) >> 16);
}
__device__ __forceinline__ float bh2f(u16 h) {
  return __uint_as_float(((u32)h) << 16);
}
// async global->LDS, 16B per lane; lds ptr must be wave-uniform base
__device__ __forceinline__ void g2lds16(const void* g, void* s) {
  __builtin_amdgcn_global_load_lds((const __attribute__((address_space(1))) void*)g,
                                   (__attribute__((address_space(3))) void*)s, 16, 0, 0);
}
// Swizzle convention (ALL plane writers/readers): planes are row-major rows of
// K bf16.  Within each 64B k-block (32 values), the 16B chunk holding logical
// chunk c (c=0..3) is stored at position c ^ ((row>>1)&3).
__device__ __forceinline__ int swz_cb(int k0, int row) {
  return ((k0 >> 3) & 3) ^ ((row >> 1) & 3);
}

// ---------------------------------------------------------------------------
// f32 GEMM fallback (tier <2): C[m,n] = sum_k A[m,k]*B[n,k]
// ---------------------------------------------------------------------------
__global__ __launch_bounds__(256)
void gemm64(const float* __restrict__ A, int lda,
            const float* __restrict__ B, int ldb, int K,
            float* __restrict__ C, int ldc)
{
  __shared__ float As[16][64];
  __shared__ float Bs[16][64];
  const int t  = threadIdx.x;
  const int bm = blockIdx.x * 64, bn = blockIdx.y * 64;
  const int tm = t & 15, tn = t >> 4;
  const int lr = t >> 2;
  const int lk = (t & 3) * 4;
  float acc[4][4];
#pragma unroll
  for (int r = 0; r < 4; r++)
#pragma unroll
    for (int c = 0; c < 4; c++) acc[r][c] = 0.f;

  for (int kt = 0; kt < K; kt += 16) {
    float4 a4 = *(const float4*)(A + (size_t)(bm + lr) * lda + kt + lk);
    float4 b4 = *(const float4*)(B + (size_t)(bn + lr) * ldb + kt + lk);
    As[lk+0][lr] = a4.x; As[lk+1][lr] = a4.y; As[lk+2][lr] = a4.z; As[lk+3][lr] = a4.w;
    Bs[lk+0][lr] = b4.x; Bs[lk+1][lr] = b4.y; Bs[lk+2][lr] = b4.z; Bs[lk+3][lr] = b4.w;
    __syncthreads();
#pragma unroll
    for (int k = 0; k < 16; k++) {
      float av[4], bv[4];
#pragma unroll
      for (int r = 0; r < 4; r++) av[r] = As[k][tm*4 + r];
#pragma unroll
      for (int c = 0; c < 4; c++) bv[c] = Bs[k][tn*4 + c];
#pragma unroll
      for (int r = 0; r < 4; r++)
#pragma unroll
        for (int c = 0; c < 4; c++) acc[r][c] += av[r] * bv[c];
    }
    __syncthreads();
  }
#pragma unroll
  for (int r = 0; r < 4; r++)
#pragma unroll
    for (int c = 0; c < 4; c++)
      C[(size_t)(bm + tm*4 + r) * ldc + bn + tn*4 + c] = acc[r][c];
}

// ---- fallback small kernels (tier <3) ----
__global__ __launch_bounds__(256)
void lab_kernel(const float* __restrict__ label, const float* __restrict__ W2,
                float* __restrict__ lab)
{
  int lt = blockIdx.x;
  __shared__ __align__(16) float le[NE];
  for (int e = threadIdx.x; e < NE; e += 256) le[e] = label[(size_t)lt*NE + e];
  __syncthreads();
  for (int o = threadIdx.x; o < NH; o += 256) {
    const float4* wr = (const float4*)(W2 + (size_t)o*NE);
    const float4* l4 = (const float4*)le;
    float s = 0.f;
    for (int e = 0; e < NE/4; e++) {
      float4 a = l4[e], b = wr[e];
      s += a.x*b.x + a.y*b.y + a.z*b.z + a.w*b.w;
    }
    lab[(size_t)lt*NH + o] = s;
  }
}

__global__ __launch_bounds__(256)
void LB_kernel(const float* __restrict__ lab, const float* __restrict__ W5,
               float* __restrict__ LB)
{
  int lt = blockIdx.x;
  __shared__ __align__(16) float lr[NH];
  for (int h = threadIdx.x; h < NH; h += 256) lr[h] = lab[(size_t)lt*NH + h];
  __syncthreads();
  for (int o = threadIdx.x; o < NH; o += 256) {
    const float4* wr = (const float4*)(W5 + (size_t)o*3072 + NH);
    const float4* l4 = (const float4*)lr;
    float s = 0.f;
    for (int h = 0; h < NH/4; h++) {
      float4 a = l4[h], b = wr[h];
      s += a.x*b.x + a.y*b.y + a.z*b.z + a.w*b.w;
    }
    LB[(size_t)lt*NH + o] = s;
  }
}

__global__ __launch_bounds__(256)
void scores_kernel(const float* __restrict__ tkn, const float* __restrict__ lab,
                   const float* __restrict__ lmask, const float* __restrict__ imask,
                   float* __restrict__ aw, float* __restrict__ b_in)
{
  int bs = blockIdx.x;
  __shared__ __align__(16) float trow[NH];
  __shared__ float sc[NLT];
  __shared__ float mL[NL], iL[NL];
  for (int h = threadIdx.x; h < NH; h += 256) trow[h] = tkn[(size_t)bs*NH + h];
  __syncthreads();
  int j = threadIdx.x;
  if (j < NLT) {
    const float4* lrow = (const float4*)(lab + (size_t)j*NH);
    const float4* t4   = (const float4*)trow;
    float s = 0.f;
    for (int h = 0; h < NH/4; h++) {
      float4 a = t4[h], b = lrow[h];
      s += a.x*b.x + a.y*b.y + a.z*b.z + a.w*b.w;
    }
    s += (1.0f - lmask[j]) * NEGV;
    sc[j] = s;
  }
  __syncthreads();
  if (j < NL) {
    float m = sc[j*8];
    for (int t = 1; t < 8; t++) m = fmaxf(m, sc[j*8 + t]);
    float ssum = 0.f;
    for (int t = 0; t < 8; t++) ssum += __expf(sc[j*8 + t] - m);
    mL[j] = m; iL[j] = 1.0f / ssum;
    b_in[(size_t)bs*NL + j] = m + (1.0f - imask[bs]) * NEGV;
  }
  __syncthreads();
  if (j < NLT) aw[(size_t)bs*NLT + j] = __expf(sc[j] - mL[j >> 3]) * iL[j >> 3];
}

// tier3: softmax/aw from precomputed sc[BS_, NLT]
__global__ __launch_bounds__(256)
void aw_kernel(const float* __restrict__ sc_in, const float* __restrict__ lmask,
               const float* __restrict__ imask, float* __restrict__ aw,
               float* __restrict__ b_in)
{
  int bs = blockIdx.x;
  __shared__ float sc[NLT];
  __shared__ float mL[NL], iL[NL];
  int j = threadIdx.x;
  if (j < NLT) sc[j] = sc_in[(size_t)bs*NLT + j] + (1.0f - lmask[j]) * NEGV;
  __syncthreads();
  if (j < NL) {
    float m = sc[j*8];
    for (int t = 1; t < 8; t++) m = fmaxf(m, sc[j*8 + t]);
    float ssum = 0.f;
    for (int t = 0; t < 8; t++) ssum += __expf(sc[j*8 + t] - m);
    mL[j] = m; iL[j] = 1.0f / ssum;
    b_in[(size_t)bs*NL + j] = m + (1.0f - imask[bs]) * NEGV;
  }
  __syncthreads();
  if (j < NLT) aw[(size_t)bs*NLT + j] = __expf(sc[j] - mL[j >> 3]) * iL[j >> 3];
}

__global__ __launch_bounds__(256)
void softs_kernel(const float* __restrict__ b_in, float* __restrict__ bc)
{
  int b = blockIdx.x / NL, l = blockIdx.x % NL;
  int s = threadIdx.x;
  __shared__ float red[256];
  float v = b_in[((size_t)b*NS + s)*NL + l];
  red[s] = v; __syncthreads();
  for (int off = 128; off > 0; off >>= 1) {
    if (s < off) red[s] = fmaxf(red[s], red[s + off]);
    __syncthreads();
  }
  float m = red[0]; __syncthreads();
  float e = __expf(v - m);
  red[s] = e; __syncthreads();
  for (int off = 128; off > 0; off >>= 1) {
    if (s < off) red[s] += red[s + off];
    __syncthreads();
  }
  bc[((size_t)b*NS + s)*NL + l] = e / red[0];
}

// q2c[b,l,h] = sum_s bc[b,s,l]*tkn[b,s,h].  Grid (NB, NH/128).
__global__ __launch_bounds__(256)
void q2c_kernel2(const float* __restrict__ bc, const float* __restrict__ tkn,
                 float* __restrict__ q2c)
{
  const int b  = blockIdx.x;
  const int h0 = blockIdx.y * 128;
  const int t  = threadIdx.x;
  const int th = t & 127, half = t >> 7;
  __shared__ __align__(16) float bcS[NS*NL];        // 20 KB
  __shared__ __align__(16) float4 part[2*5*128];    // 20 KB
  for (int i = t; i < NS*NL; i += 256) bcS[i] = bc[(size_t)b*NS*NL + i];
  __syncthreads();
  float4 acc[5];
#pragma unroll
  for (int g = 0; g < 5; g++) acc[g] = {0.f, 0.f, 0.f, 0.f};
  const int h = h0 + th;
  for (int s = half*128; s < half*128 + 128; s++) {
    float tv = tkn[((size_t)b*NS + s)*NH + h];
    const float4* bl4 = (const float4*)(bcS + s*NL);
#pragma unroll
    for (int g = 0; g < 5; g++) {
      float4 w = bl4[g];
      acc[g].x += w.x*tv; acc[g].y += w.y*tv; acc[g].z += w.z*tv; acc[g].w += w.w*tv;
    }
  }
#pragma unroll
  for (int g = 0; g < 5; g++) part[(half*5 + g)*128 + th] = acc[g];
  __syncthreads();
  if (half == 0) {
#pragma unroll
    for (int g = 0; g < 5; g++) {
      float4 a = part[g*128 + th], c = part[(5 + g)*128 + th];
#pragma unroll
      for (int cc = 0; cc < 4; cc++) {
        int l = g*4 + cc;
        float v = ((const float*)&a)[cc] + ((const float*)&c)[cc];
        q2c[((size_t)(b*NL + l))*NH + h] = v;
      }
    }
  }
}

// ---------------------------------------------------------------------------
// OLD fused_out — fallback when ws can't even hold the fused-GEMM planes.
// ---------------------------------------------------------------------------
__global__ __launch_bounds__(256)
void fused_out(const float* __restrict__ tkn, const float* __restrict__ lab,
               const float* __restrict__ aw, const float* __restrict__ q2c,
               const float* __restrict__ T1, const float* __restrict__ LB,
               const float* __restrict__ W5, const float* __restrict__ b5,
               float* __restrict__ outp)
{
  const int t  = threadIdx.x;
  const int sq = blockIdx.x & 3;
  const int l  = (blockIdx.x >> 2) % NL;
  const int b  = blockIdx.x / (4 * NL);
  const int o0 = blockIdx.y * 64;
  const int s0 = sq * 64;
  const int tm = t & 15, tn = t >> 4;
  const int lr = t >> 2;
  const int lk = (t & 3) * 4;

  __shared__ float A1s[16][64];
  __shared__ float A2s[16][64];
  __shared__ float Cs[16][64];
  __shared__ float Ds[16][64];
  __shared__ float labS[NT][16];
  __shared__ float q2cS[16];
  __shared__ float awS[64][NT];
  __shared__ float LBS[NT][64];
  __shared__ float b5S[64];

  for (int i = t; i < 64*NT; i += 256) {
    int m = i >> 3, tt = i & 7;
    awS[m][tt] = aw[(size_t)(b*NS + s0 + m) * NLT + l*NT + tt];
  }
  for (int i = t; i < NT*64; i += 256) {
    int tt = i >> 6, n = i & 63;
    LBS[tt][n] = LB[(size_t)(l*NT + tt) * NH + o0 + n];
  }
  if (t < 64) b5S[t] = b5[o0 + t];

  float acc[4][4];
#pragma unroll
  for (int r = 0; r < 4; r++)
#pragma unroll
    for (int c = 0; c < 4; c++) acc[r][c] = 0.f;

  for (int kt = 0; kt < NH; kt += 16) {
    if (t < 128) { int tt = t >> 4, k = t & 15; labS[tt][k] = lab[(size_t)(l*NT + tt)*NH + kt + k]; }
    if (t < 16)  q2cS[t] = q2c[(size_t)(b*NL + l)*NH + kt + t];
    {
      float4 c4 = *(const float4*)(W5 + (size_t)(o0 + lr)*3072 + 1536 + kt + lk);
      Cs[lk+0][lr] = c4.x; Cs[lk+1][lr] = c4.y; Cs[lk+2][lr] = c4.z; Cs[lk+3][lr] = c4.w;
      float4 d4 = *(const float4*)(W5 + (size_t)(o0 + lr)*3072 + 2304 + kt + lk);
      Ds[lk+0][lr] = d4.x; Ds[lk+1][lr] = d4.y; Ds[lk+2][lr] = d4.z; Ds[lk+3][lr] = d4.w;
    }
    __syncthreads();
    {
      float4 t4 = *(const float4*)(tkn + (size_t)(b*NS + s0 + lr)*NH + kt + lk);
      float tv[4] = {t4.x, t4.y, t4.z, t4.w};
#pragma unroll
      for (int j = 0; j < 4; j++) {
        int k = lk + j;
        float c2 = 0.f;
#pragma unroll
        for (int tt = 0; tt < NT; tt++) c2 += awS[lr][tt] * labS[tt][k];
        A1s[k][lr] = tv[j] * c2;
        A2s[k][lr] = tv[j] * q2cS[k];
      }
    }
    __syncthreads();
#pragma unroll
    for (int k = 0; k < 16; k++) {
      float a1[4], a2[4], wc[4], wd[4];
#pragma unroll
      for (int r = 0; r < 4; r++) { a1[r] = A1s[k][tm*4 + r]; a2[r] = A2s[k][tm*4 + r]; }
#pragma unroll
      for (int c = 0; c < 4; c++) { wc[c] = Cs[k][tn*4 + c]; wd[c] = Ds[k][tn*4 + c]; }
#pragma unroll
      for (int r = 0; r < 4; r++)
#pragma unroll
        for (int c = 0; c < 4; c++)
          acc[r][c] += a1[r]*wc[c] + a2[r]*wd[c];
    }
    __syncthreads();
  }

#pragma unroll
  for (int r = 0; r < 4; r++) {
    int m = tm*4 + r;
    int s = s0 + m;
    size_t orow = ((size_t)(b*NS + s)*NL + l)*NH + o0;
    const float* T1r = T1 + (size_t)(b*NS + s)*NH + o0;
#pragma unroll
    for (int c = 0; c < 4; c++) {
      int n = tn*4 + c;
      float v = acc[r][c] + T1r[n] + b5S[n];
#pragma unroll
      for (int tt = 0; tt < NT; tt++) v += awS[m][tt] * LBS[tt][n];
      outp[orow + n] = fast_tanh(v);
    }
  }
}

// ---------------------------------------------------------------------------
// Generic f32 -> bf16 hi/lo split into the swizzled plane layout (fallback).
// ---------------------------------------------------------------------------
__global__ __launch_bounds__(256)
void prep_split(const float* __restrict__ src, int srcStride, int k0src, int K,
                u16* __restrict__ hi, u16* __restrict__ lo)
{
  const int r = blockIdx.x;
  const float* srow = src + (size_t)r*srcStride + k0src;
  for (int c = threadIdx.x; c < (K >> 3); c += 256) {
    int k0 = c * 8;
    union { u16 a[8]; short8v v; } ph, pl;
#pragma unroll
    for (int j = 0; j < 8; j++) {
      float v = srow[k0 + j];
      u16 h = f2bh(v);
      ph.a[j] = h;
      pl.a[j] = f2bh(v - bh2f(h));
    }
    size_t base = (size_t)r*K + (size_t)(k0 >> 5)*32 + swz_cb(k0, r)*8;
    *(short8v*)(hi + base) = ph.v;
    *(short8v*)(lo + base) = pl.v;
  }
}

__global__ __launch_bounds__(256)
void prep_split_pad(const float* __restrict__ src, int srcStride, int Ksrc, int Rsrc,
                    int K, u16* __restrict__ hi, u16* __restrict__ lo)
{
  const int r = blockIdx.x;
  const bool rok = r < Rsrc;
  const float* srow = src + (size_t)r*srcStride;
  for (int c = threadIdx.x; c < (K >> 3); c += 256) {
    int k0 = c * 8;
    union { u16 a[8]; short8v v; } ph, pl;
#pragma unroll
    for (int j = 0; j < 8; j++) {
      float v = (rok && (k0 + j) < Ksrc) ? srow[k0 + j] : 0.f;
      u16 h = f2bh(v);
      ph.a[j] = h;
      pl.a[j] = f2bh(v - bh2f(h));
    }
    size_t base = (size_t)r*K + (size_t)(k0 >> 5)*32 + swz_cb(k0, r)*8;
    *(short8v*)(hi + base) = ph.v;
    *(short8v*)(lo + base) = pl.v;
  }
}

// tier3: ALL independent input/weight splits in ONE launch.  grid (2048, 7).
__global__ __launch_bounds__(256)
void prep_weights(const float* __restrict__ W5, const float* __restrict__ W1,
                  const float* __restrict__ W2, const float* __restrict__ token,
                  const float* __restrict__ label,
                  u16* __restrict__ Wh,   u16* __restrict__ Wl,
                  u16* __restrict__ w1h,  u16* __restrict__ w1l,
                  u16* __restrict__ wb1h, u16* __restrict__ wb1l,
                  u16* __restrict__ wb2h, u16* __restrict__ wb2l,
                  u16* __restrict__ w2h,  u16* __restrict__ w2l,
                  u16* __restrict__ tokh, u16* __restrict__ tokl,
                  u16* __restrict__ labeh, u16* __restrict__ label_)
{
  const int job = blockIdx.y;
  const int r = blockIdx.x;
  const float* src; int stride, Ksrc, K, Rsrc, Rplane; u16 *hi, *lo;
  switch (job) {
    case 0: src = W5 + 1536; stride = 3072; Ksrc = 1536; K = KTOT; Rsrc = NH;  Rplane = NH;   hi = Wh;   lo = Wl;   break;
    case 1: src = W1;        stride = NH;   Ksrc = NH;   K = NH;   Rsrc = NH;  Rplane = NH;   hi = w1h;  lo = w1l;  break;
    case 2: src = W5;        stride = 3072; Ksrc = NH;   K = NH;   Rsrc = NH;  Rplane = NH;   hi = wb1h; lo = wb1l; break;
    case 3: src = W5 + NH;   stride = 3072; Ksrc = NH;   K = NH;   Rsrc = NH;  Rplane = NH;   hi = wb2h; lo = wb2l; break;
    case 4: src = W2;        stride = NE;   Ksrc = NE;   K = NEP;  Rsrc = NH;  Rplane = NH;   hi = w2h;  lo = w2l;  break;
    case 5: src = token;     stride = NH;   Ksrc = NH;   K = NH;   Rsrc = BS_; Rplane = BS_;  hi = tokh; lo = tokl; break;
    default: src = label;    stride = NE;   Ksrc = NE;   K = NEP;  Rsrc = NLT; Rplane = NLTP; hi = labeh; lo = label_; break;
  }
  if (r >= Rplane) return;
  const bool rok = r < Rsrc;
  const float* srow = src + (size_t)r*stride;
  for (int c = threadIdx.x; c < (K >> 3); c += 256) {
    int k0 = c * 8;
    union { u16 a[8]; short8v v; } ph, pl;
#pragma unroll
    for (int j = 0; j < 8; j++) {
      float v = (rok && (k0 + j) < Ksrc) ? srow[k0 + j] : 0.f;
      u16 h = f2bh(v);
      ph.a[j] = h;
      pl.a[j] = f2bh(v - bh2f(h));
    }
    size_t base = (size_t)r*K + (size_t)(k0 >> 5)*32 + swz_cb(k0, r)*8;
    *(short8v*)(hi + base) = ph.v;
    *(short8v*)(lo + base) = pl.v;
  }
}

// A' rows ordered [l][bs]:  A'[row][0:768) = tkn.*c2q,  [768:1536) = tkn.*q2c.
// ROUND-8: single bf16 plane (no Al) — the W-side stays split (Wh+Wl), so the
// dropped correction is only sum_k (A-Ah)*W ~ 1e-3 max, under the pipeline's
// existing 2^-8 error floor.  Halves write traffic AND the split VALU work.
__global__ __launch_bounds__(256)
void aprep(const float* __restrict__ tkn, const float* __restrict__ lab,
           const float* __restrict__ aw, const float* __restrict__ q2c,
           u16* __restrict__ Ah)
{
  const int l   = blockIdx.x >> 4;
  const int bs0 = (blockIdx.x & 15) << 7;     // 128-row chunk, same b throughout
  const int b   = bs0 >> 8;
  const int t   = threadIdx.x;
  __shared__ float labS[NT][NH];
  __shared__ float q2cS[NH];
  __shared__ float awT[NT][128];
  for (int i = t; i < NT*NH; i += 256) { int tt = i / NH, k = i % NH; labS[tt][k] = lab[(size_t)(l*NT+tt)*NH + k]; }
  for (int i = t; i < NH; i += 256) q2cS[i] = q2c[(size_t)(b*NL + l)*NH + i];
  for (int i = t; i < NT*128; i += 256) { int tt = i >> 7, m = i & 127; awT[tt][m] = aw[(size_t)(bs0+m)*NLT + l*NT + tt]; }
  __syncthreads();

  const int w    = t >> 6;        // wave 0..3
  const int l6   = t & 63;
  const int mloc = l6 >> 4;       // 0..3   (row within wave tile)
  const int c16  = l6 & 15;       // 0..15  (chunk within wave tile)

  for (int ii = 0; ii < 48; ii++) {
    const int ct = ii % 6, rt = ii / 6;
    const int m  = rt*16 + w*4 + mloc;
    const int c  = ct*16 + c16;
    const int k0 = c * 8;
    const int bs = bs0 + m;
    const float* trow = tkn + (size_t)bs*NH + k0;
    float4 t4a = *(const float4*)(trow);
    float4 t4b = *(const float4*)(trow + 4);
    float tv[8] = {t4a.x, t4a.y, t4a.z, t4a.w, t4b.x, t4b.y, t4b.z, t4b.w};
    float awv[NT];
#pragma unroll
    for (int tt = 0; tt < NT; tt++) awv[tt] = awT[tt][m];

    union { u16 a[8]; short8v v; } h1, h2;
#pragma unroll
    for (int j = 0; j < 8; j++) {
      float cq = 0.f;
#pragma unroll
      for (int tt = 0; tt < NT; tt++) cq += awv[tt] * labS[tt][k0+j];
      h1.a[j] = f2bh(tv[j] * cq);
      h2.a[j] = f2bh(tv[j] * q2cS[k0+j]);
    }
    size_t rowbase = ((size_t)l*BS_ + bs) * KTOT;
    size_t d1 = rowbase + (size_t)(k0 >> 5)*32 + swz_cb(k0, m)*8;
    size_t d2 = d1 + NH;
    *(short8v*)(Ah + d1) = h1.v;
    *(short8v*)(Ah + d2) = h2.v;
  }
}

// ---------------------------------------------------------------------------
// Plain 3-term MFMA GEMM, double-buffered (BK=32, 2x32KB LDS, counted vmcnt).
// (verified; unchanged — small dispatches only; kept 3-term because tkn feeds
// the softmax path where exp() amplifies error)
// ---------------------------------------------------------------------------
template<int OUT>
__global__ __launch_bounds__(256)
void mfma_gemm_plainT(const u16* __restrict__ AhG, const u16* __restrict__ AlG,
                      const u16* __restrict__ BhG, const u16* __restrict__ BlG,
                      int K, float* __restrict__ C, int ldc, int Mv, int Nv,
                      u16* __restrict__ Ph, u16* __restrict__ Pl, int Kp)
{
  __shared__ __align__(16) char lds[65536];

  const int m0 = blockIdx.x * 128, n0 = blockIdx.y * 128;
  const int t = threadIdx.x;
  const int wv = t >> 6, lane = t & 63;
  const int wm0 = (wv >> 1) << 6;
  const int wn0 = (wv & 1) << 6;
  const int fr = lane & 15;
  const int g  = lane >> 4;
  const int r0 = wv*32 + (lane >> 2);
  const int cpos = (lane & 3) * 16;

  const size_t rowb = (size_t)K * 2;
  const char* gAh = (const char*)AhG + (size_t)m0 * rowb;
  const char* gAl = (const char*)AlG + (size_t)m0 * rowb;
  const char* gBh = (const char*)BhG + (size_t)n0 * rowb;
  const char* gBl = (const char*)BlG + (size_t)n0 * rowb;
  const size_t gs = 16 * rowb;

  f32x4 acc[4][4];
  f32x4 zz = {0.f, 0.f, 0.f, 0.f};
#pragma unroll
  for (int i = 0; i < 4; i++)
#pragma unroll
    for (int j = 0; j < 4; j++) acc[i][j] = zz;

  auto stage = [&](int kb, int half) {
    size_t ga = (size_t)r0 * rowb + (size_t)kb * 64 + cpos;
    char* base = lds + half*32768 + wv*2048;
    g2lds16(gAh + ga, base);           g2lds16(gAh + ga + gs, base + 1024);
    g2lds16(gAl + ga, base + 8192);    g2lds16(gAl + ga + gs, base + 9216);
    g2lds16(gBh + ga, base + 16384);   g2lds16(gBh + ga + gs, base + 17408);
    g2lds16(gBl + ga, base + 24576);   g2lds16(gBl + ga + gs, base + 25600);
  };

  const int nkb = K >> 5;
  stage(0, 0);
  for (int kb = 0; kb < nkb; kb++) {
    const int cur = kb & 1;
    if (kb + 1 < nkb) {
      stage(kb + 1, cur ^ 1);
      asm volatile("s_waitcnt vmcnt(8)" ::: "memory");
    } else {
      asm volatile("s_waitcnt vmcnt(0)" ::: "memory");
    }
    __builtin_amdgcn_s_barrier();
    __builtin_amdgcn_sched_barrier(0);

    const char* ldsAh = lds + cur*32768;
    const char* ldsAl = ldsAh + 8192;
    const char* ldsBh = ldsAh + 16384;
    const char* ldsBl = ldsAh + 24576;
    const int xk = ((g ^ ((fr >> 1) & 3)) << 4);
    short8v bh[4], bl[4];
#pragma unroll
    for (int j = 0; j < 4; j++) {
      int n = wn0 + j*16 + fr;
      bh[j] = *(const short8v*)(ldsBh + n*64 + xk);
      bl[j] = *(const short8v*)(ldsBl + n*64 + xk);
    }
    __builtin_amdgcn_s_setprio(1);
#pragma unroll
    for (int i = 0; i < 4; i++) {
      int m = wm0 + i*16 + fr;
      short8v ah = *(const short8v*)(ldsAh + m*64 + xk);
      short8v al = *(const short8v*)(ldsAl + m*64 + xk);
#pragma unroll
      for (int j = 0; j < 4; j++) {
        acc[i][j] = __builtin_amdgcn_mfma_f32_16x16x32_bf16(ah, bh[j], acc[i][j], 0, 0, 0);
        acc[i][j] = __builtin_amdgcn_mfma_f32_16x16x32_bf16(ah, bl[j], acc[i][j], 0, 0, 0);
        acc[i][j] = __builtin_amdgcn_mfma_f32_16x16x32_bf16(al, bh[j], acc[i][j], 0, 0, 0);
      }
    }
    __builtin_amdgcn_s_setprio(0);
    __builtin_amdgcn_sched_barrier(0);
    __builtin_amdgcn_s_barrier();
  }

  const int lr4 = (lane >> 4) * 4;
#pragma unroll
  for (int i = 0; i < 4; i++) {
#pragma unroll
    for (int r = 0; r < 4; r++) {
      int m = m0 + wm0 + i*16 + lr4 + r;
      float* Cr = C + (size_t)m * ldc + n0;
#pragma unroll
      for (int j = 0; j < 4; j++) {
        int nl = wn0 + j*16 + fr;
        int n = n0 + nl;
        float v = acc[i][j][r];
        if (m < Mv && n < Nv) Cr[nl] = v;
        if constexpr (OUT == 1) {
          u16 h = f2bh(v);
          u16 lo2 = f2bh(v - bh2f(h));
          size_t po = (size_t)m*Kp + (size_t)((n >> 5) << 5)
                    + ((((n >> 3) & 3) ^ ((m >> 1) & 3)) << 3) + (n & 7);
          Ph[po] = h;
          Pl[po] = lo2;
        }
      }
    }
  }
}

// ---------------------------------------------------------------------------
// Fused MFMA GEMM + epilogue — ROUND-8: 2-term split (Ah single plane; W
// split Wh+Wl).  3 planes/K-step -> LDS 24KB/buffer, 48KB dbuf -> 3 blocks/CU
// (24 waves, 6/SIMD).  MFMA work -33%.  Same dbuf+counted-vmcnt skeleton.
// ---------------------------------------------------------------------------
__global__ __launch_bounds__(512, 6)
void mfma_gemm(const u16* __restrict__ AhG,
               const u16* __restrict__ WhG, const u16* __restrict__ WlG,
               const float* __restrict__ T1, const float* __restrict__ LBt,
               const float* __restrict__ aw, const float* __restrict__ b5,
               float* __restrict__ outp)
{
  __shared__ __align__(16) char lds[49152];

  int id = blockIdx.x;
  int swz = (id & 7) * 240 + (id >> 3);
  const int nb  = swz % 6;
  const int mbk = swz / 6;
  const int l   = mbk >> 4;
  const int bs0 = (mbk & 15) << 7;
  const int o0  = nb << 7;

  const int t = threadIdx.x;
  const int wv = t >> 6, lane = t & 63;
  const int wm0 = (wv >> 2) << 6;      // 0 / 64      (2 M-groups of waves)
  const int wn0 = (wv & 3) << 5;       // 0/32/64/96  (4 N-groups of waves)
  const int fr = lane & 15;
  const int g  = lane >> 4;

  const char* gAh = (const char*)AhG + ((size_t)l*BS_ + bs0) * (KTOT*2);
  const char* gWh = (const char*)WhG + (size_t)o0 * (KTOT*2);
  const char* gWl = (const char*)WlG + (size_t)o0 * (KTOT*2);

  f32x4 acc[4][2];
  f32x4 zz = {0.f, 0.f, 0.f, 0.f};
#pragma unroll
  for (int i = 0; i < 4; i++)
#pragma unroll
    for (int j = 0; j < 2; j++) acc[i][j] = zz;

  // staging: 512 threads x 3 planes x 16B = 24KB/step.  Per wave 1 instr per
  // plane (wave-uniform LDS base wv*1024 + implicit lane*16).  Global:
  // row = t>>2 (0..127), chunk = (t&3)*16 -- matches linear LDS layout.
  auto stage = [&](int kb, int half) {
    size_t ga = (size_t)(t >> 2) * (KTOT*2) + (size_t)kb * 64 + (t & 3) * 16;
    char* base = lds + half*24576 + wv*1024;
    g2lds16(gAh + ga, base);
    g2lds16(gWh + ga, base + 8192);
    g2lds16(gWl + ga, base + 16384);
  };

  const int nkb = KTOT/32;
  stage(0, 0);
  for (int kb = 0; kb < nkb; kb++) {
    const int cur = kb & 1;
    if (kb + 1 < nkb) {
      stage(kb + 1, cur ^ 1);
      asm volatile("s_waitcnt vmcnt(3)" ::: "memory");   // 3 outstanding = next tile
    } else {
      asm volatile("s_waitcnt vmcnt(0)" ::: "memory");
    }
    __builtin_amdgcn_s_barrier();
    __builtin_amdgcn_sched_barrier(0);

    const char* ldsAh = lds + cur*24576;
    const char* ldsWh = ldsAh + 8192;
    const char* ldsWl = ldsAh + 16384;
    const int xk = ((g ^ ((fr >> 1) & 3)) << 4);
    short8v wh[2], wl[2];
#pragma unroll
    for (int j = 0; j < 2; j++) {
      int n = wn0 + j*16 + fr;
      wh[j] = *(const short8v*)(ldsWh + n*64 + xk);
      wl[j] = *(const short8v*)(ldsWl + n*64 + xk);
    }
    __builtin_amdgcn_s_setprio(1);
#pragma unroll
    for (int i = 0; i < 4; i++) {
      int m = wm0 + i*16 + fr;
      short8v ah = *(const short8v*)(ldsAh + m*64 + xk);
#pragma unroll
      for (int j = 0; j < 2; j++) {
        acc[i][j] = __builtin_amdgcn_mfma_f32_16x16x32_bf16(ah, wh[j], acc[i][j], 0, 0, 0);
        acc[i][j] = __builtin_amdgcn_mfma_f32_16x16x32_bf16(ah, wl[j], acc[i][j], 0, 0, 0);
      }
    }
    __builtin_amdgcn_s_setprio(0);
    __builtin_amdgcn_sched_barrier(0);
    __builtin_amdgcn_s_barrier();
  }

  // epilogue: reuse LDS for LB slice / aw / b5 (single l per block).
  float* LBs = (float*)lds;               // [8][128]
  float* aws = (float*)(lds + 4096);      // [128][8]
  float* b5s = (float*)(lds + 8192);      // [128]
  for (int i = t; i < NT*128; i += 512) { int tt = i >> 7, n = i & 127; LBs[i] = LBt[(size_t)(l*NT+tt)*NH + o0 + n]; }
  for (int i = t; i < 128*NT; i += 512) { int m = i >> 3, tt = i & 7; aws[i] = aw[(size_t)(bs0+m)*NLT + l*NT + tt]; }
  if (t < 128) b5s[t] = b5[o0 + t];
  __syncthreads();

  const int lr4 = (lane >> 4) * 4;        // C/D: row = (lane>>4)*4 + reg, col = lane&15
#pragma unroll
  for (int i = 0; i < 4; i++) {
#pragma unroll
    for (int r = 0; r < 4; r++) {
      int m = wm0 + i*16 + lr4 + r;
      int bs = bs0 + m;
      const float* T1r = T1 + (size_t)bs*NH + o0;
      size_t orow = ((size_t)bs*NL + l)*NH + o0;
      float awv[NT];
#pragma unroll
      for (int tt = 0; tt < NT; tt++) awv[tt] = aws[m*8 + tt];
#pragma unroll
      for (int j = 0; j < 2; j++) {
        int n = wn0 + j*16 + fr;
        float v = acc[i][j][r] + T1r[n] + b5s[n];
#pragma unroll
        for (int tt = 0; tt < NT; tt++) v += awv[tt] * LBs[tt*128 + n];
        outp[orow + n] = fast_tanh(v);
      }
    }
  }
}

extern "C" void kernel_launch(void* const* d_in, const int* in_sizes, int n_in,
                              void* d_out, int out_size, void* d_ws, size_t ws_size,
                              hipStream_t stream)
{
  const float* token = (const float*)d_in[0];
  const float* label = (const float*)d_in[1];
  const float* imask = (const float*)d_in[2];
  const float* lmask = (const float*)d_in[3];
  const float* W1    = (const float*)d_in[4];
  const float* W2    = (const float*)d_in[5];
  const float* W5    = (const float*)d_in[6];
  const float* b5    = (const float*)d_in[7];
  float* outp = (float*)d_out;

  // ---- workspace layout (identical to Round 7 so tier thresholds match;
  //      AlG is allocated but no longer written/read) ----
  char* p = (char*)d_ws;
  float* tkn  = (float*)p; p += (size_t)BS_*NH*4;
  float* T1   = (float*)p; p += (size_t)BS_*NH*4;
  float* lab  = (float*)p; p += (size_t)NLT*NH*4;
  float* LB   = (float*)p; p += (size_t)NLT*NH*4;
  float* aw   = (float*)p; p += (size_t)BS_*NLT*4;
  float* b_in = (float*)p; p += (size_t)BS_*NL*4;
  float* bc   = (float*)p; p += (size_t)BS_*NL*4;
  float* q2c  = (float*)p; p += (size_t)NL*NB*NH*4;

  size_t baseBytes = (size_t)(p - (char*)d_ws);
  const size_t needA = (size_t)NL * BS_ * KTOT * 2;   // 125,829,120 each
  const size_t needW = (size_t)NH * KTOT * 2;         //   2,359,296 each
  bool tier1 = ws_size >= baseBytes + 2*needA + 2*needW;
  u16 *AhG = 0, *AlG = 0, *WhG = 0, *WlG = 0;
  if (tier1) {
    AhG = (u16*)p; p += needA;
    AlG = (u16*)p; p += needA;   // unused in 2-term scheme (kept for layout)
    WhG = (u16*)p; p += needW;
    WlG = (u16*)p; p += needW;
  }
  (void)AlG;
  // tier2: bf16 planes for the two pre-GEMMs
  const size_t szTok = (size_t)BS_*NH*2;   // 3,145,728
  const size_t szW   = (size_t)NH*NH*2;    // 1,179,648
  size_t extra2 = 2*szTok*2 + 2*szW*2;
  bool tier2 = tier1 && (ws_size >= (size_t)(p - (char*)d_ws) + extra2);
  u16 *tokh=0,*tokl=0,*w1h=0,*w1l=0,*wb1h=0,*wb1l=0,*tknh=0,*tknl=0;
  if (tier2) {
    tokh = (u16*)p; p += szTok;  tokl = (u16*)p; p += szTok;
    w1h  = (u16*)p; p += szW;    w1l  = (u16*)p; p += szW;
    wb1h = (u16*)p; p += szW;    wb1l = (u16*)p; p += szW;
    tknh = (u16*)p; p += szTok;  tknl = (u16*)p; p += szTok;
  }
  // tier3: lab/scores/LB on MFMA (padded planes)
  const size_t szWb2   = (size_t)NH*NH*2;        // 1,179,648
  const size_t szW2P   = (size_t)NH*NEP*2;       //   491,520
  const size_t szLabel = (size_t)NLTP*NEP*2;     //   163,840
  const size_t szLabP  = (size_t)NLTP*NH*2;      //   393,216
  const size_t szSc    = (size_t)BS_*NLT*4;      // 1,310,720
  size_t extra3 = 2*szWb2 + 2*szW2P + 2*szLabel + 2*szLabP + szSc;
  bool tier3 = tier2 && (ws_size >= (size_t)(p - (char*)d_ws) + extra3);
  u16 *wb2h=0,*wb2l=0,*w2h=0,*w2l=0,*labeh=0,*label_=0,*labh=0,*labl=0;
  float* sc = 0;
  if (tier3) {
    wb2h = (u16*)p; p += szWb2;   wb2l = (u16*)p; p += szWb2;
    w2h  = (u16*)p; p += szW2P;   w2l  = (u16*)p; p += szW2P;
    labeh= (u16*)p; p += szLabel; label_=(u16*)p; p += szLabel;
    labh = (u16*)p; p += szLabP;  labl = (u16*)p; p += szLabP;
    sc   = (float*)p; p += szSc;
  }

  if (tier3) {
    prep_weights<<<dim3(BS_, 7), 256, 0, stream>>>(
        W5, W1, W2, token, label,
        WhG, WlG, w1h, w1l, wb1h, wb1l, wb2h, wb2l,
        w2h, w2l, tokh, tokl, labeh, label_);
    mfma_gemm_plainT<1><<<dim3(BS_/128, NH/128), 256, 0, stream>>>(
        tokh, tokl, w1h, w1l, NH, tkn, NH, BS_, NH, tknh, tknl, NH);
    mfma_gemm_plainT<0><<<dim3(BS_/128, NH/128), 256, 0, stream>>>(
        tknh, tknl, wb1h, wb1l, NH, T1, NH, BS_, NH, 0, 0, 0);
    mfma_gemm_plainT<1><<<dim3(NLTP/128, NH/128), 256, 0, stream>>>(
        labeh, label_, w2h, w2l, NEP, lab, NH, NLT, NH, labh, labl, NH);
    mfma_gemm_plainT<0><<<dim3(BS_/128, NLTP/128), 256, 0, stream>>>(
        tknh, tknl, labh, labl, NH, sc, NLT, BS_, NLT, 0, 0, 0);
    mfma_gemm_plainT<0><<<dim3(NLTP/128, NH/128), 256, 0, stream>>>(
        labh, labl, wb2h, wb2l, NH, LB, NH, NLT, NH, 0, 0, 0);
    aw_kernel<<<BS_, 256, 0, stream>>>(sc, lmask, imask, aw, b_in);
  } else {
    if (tier1)
      prep_split<<<NH, 256, 0, stream>>>(W5, 3072, 1536, KTOT, WhG, WlG);
    if (tier2) {
      prep_split<<<BS_, 256, 0, stream>>>(token, NH, 0, NH, tokh, tokl);
      prep_split<<<NH,  256, 0, stream>>>(W1,    NH, 0, NH, w1h,  w1l);
      prep_split<<<NH,  256, 0, stream>>>(W5,  3072, 0, NH, wb1h, wb1l);
      mfma_gemm_plainT<0><<<dim3(BS_/128, NH/128), 256, 0, stream>>>(
          tokh, tokl, w1h, w1l, NH, tkn, NH, BS_, NH, 0, 0, 0);
      prep_split<<<BS_, 256, 0, stream>>>(tkn, NH, 0, NH, tknh, tknl);
      mfma_gemm_plainT<0><<<dim3(BS_/128, NH/128), 256, 0, stream>>>(
          tknh, tknl, wb1h, wb1l, NH, T1, NH, BS_, NH, 0, 0, 0);
    } else {
      gemm64<<<dim3(BS_/64, NH/64), 256, 0, stream>>>(token, NH, W1, NH, NH, tkn, NH);
      gemm64<<<dim3(BS_/64, NH/64), 256, 0, stream>>>(tkn, NH, W5, 3072, NH, T1, NH);
    }
    lab_kernel<<<NLT, 256, 0, stream>>>(label, W2, lab);
    LB_kernel<<<NLT, 256, 0, stream>>>(lab, W5, LB);
    scores_kernel<<<BS_, 256, 0, stream>>>(tkn, lab, lmask, imask, aw, b_in);
  }

  softs_kernel<<<NB*NL, 256, 0, stream>>>(b_in, bc);
  q2c_kernel2<<<dim3(NB, NH/128), 256, 0, stream>>>(bc, tkn, q2c);

  if (tier1) {
    aprep<<<NL*16, 256, 0, stream>>>(tkn, lab, aw, q2c, AhG);
    mfma_gemm<<<NL*16*6, 512, 0, stream>>>(AhG, WhG, WlG, T1, LB, aw, b5, outp);
  } else {
    fused_out<<<dim3(NB*NL*4, NH/64), 256, 0, stream>>>(tkn, lab, aw, q2c, T1, LB, W5, b5, outp);
  }
}